// Round 14
// baseline (190.556 us; speedup 1.0000x reference)
//
#include <hip/hip_runtime.h>
#include <math.h>

#define BB 4
#define NN 4096
#define MM 256
#define CC 768
#define HH 12
#define DD 64
#define SCALEF 0.125f
#define LN_EPSF 1e-5f

typedef __attribute__((ext_vector_type(4))) float f32x4;
typedef __attribute__((ext_vector_type(16))) float f32x16;
typedef __attribute__((ext_vector_type(8))) _Float16 f16x8;
typedef __attribute__((ext_vector_type(4))) _Float16 f16x4;

// ---------------------------------------------------------------------------
// helpers
// ---------------------------------------------------------------------------
__device__ __forceinline__ void gldh(const _Float16* g, _Float16* l) {
    __builtin_amdgcn_global_load_lds(
        (const __attribute__((address_space(1))) void*)g,
        (__attribute__((address_space(3))) void*)l, 16, 0, 0);
}

// ---------------------------------------------------------------------------
// merged f32 -> f16 conversion over 5 segments, grid-stride, 8-wide.
// ---------------------------------------------------------------------------
__global__ __launch_bounds__(256) void conv_all(
    const float* __restrict__ x0, _Float16* __restrict__ y0, long long n0,
    const float* __restrict__ x1, _Float16* __restrict__ y1, long long n1,
    const float* __restrict__ x2, _Float16* __restrict__ y2, long long n2,
    const float* __restrict__ x3, _Float16* __restrict__ y3, long long n3,
    const float* __restrict__ x4, _Float16* __restrict__ y4, long long n4)
{
    long long i = ((long long)blockIdx.x * 256 + threadIdx.x) * 8;
    const long long total = n0 + n1 + n2 + n3 + n4;
    const long long stride = (long long)gridDim.x * 256 * 8;
    for (; i < total; i += stride) {
        const float* x; _Float16* y; long long off = i;
        if (off < n0) { x = x0; y = y0; }
        else if ((off -= n0) < n1) { x = x1; y = y1; }
        else if ((off -= n1) < n2) { x = x2; y = y2; }
        else if ((off -= n2) < n3) { x = x3; y = y3; }
        else { off -= n3; x = x4; y = y4; }
        float4 a = *(const float4*)(x + off);
        float4 b = *(const float4*)(x + off + 4);
        f16x8 o;
        o[0] = (_Float16)a.x; o[1] = (_Float16)a.y;
        o[2] = (_Float16)a.z; o[3] = (_Float16)a.w;
        o[4] = (_Float16)b.x; o[5] = (_Float16)b.y;
        o[6] = (_Float16)b.z; o[7] = (_Float16)b.w;
        *(f16x8*)(y + off) = o;
    }
}

// ---------------------------------------------------------------------------
// KV-fused fp16 MFMA GEMM, 256x128 tile, 512 threads (8 waves, 4M x 2N).
// One block computes BOTH Wk and Wv projections of a 256-row A panel.
// Staging per K-step: A 16KB (2 gldh/thr) + Bk 8KB (1) + Bv 8KB (1).
// Q-proj blocks (bid>=384) ride the same path, V result discarded.
// K path writes f16 [row][col]; V path writes f16 transposed
// [b*H+h][d][token]. No setprio (m190: hurts lockstep 2-phase GEMM).
// ---------------------------------------------------------------------------
__global__ __launch_bounds__(512) void proj_kv_f16(
    const _Float16* __restrict__ Xh,   // [16384][768]
    const _Float16* __restrict__ X2h,  // [1024][768]
    const _Float16* __restrict__ Wkh, const _Float16* __restrict__ Wqh,
    const _Float16* __restrict__ Wvh,  // each [768][768]
    const float* __restrict__ bk, const float* __restrict__ bq,
    const float* __restrict__ bv,
    _Float16* __restrict__ Klin, _Float16* __restrict__ Qlin,
    _Float16* __restrict__ Vth)        // [48][64][4096]
{
    __shared__ _Float16 As[2][256 * 32];   // 32 KB
    __shared__ _Float16 Bks[2][128 * 32];  // 16 KB
    __shared__ _Float16 Bvs[2][128 * 32];  // 16 KB

    const int bid = blockIdx.x;
    const _Float16* Ag; const _Float16* Bkg;
    const float* biask; _Float16* outk;
    bool hasV;
    int bm, bn;
    if (bid < 384) {            // K+V projections of input_tokens
        bm = bid & 63; bn = bid >> 6;      // stride-64 row-sharing -> same XCD
        Ag = Xh; Bkg = Wkh; biask = bk; outk = Klin; hasV = true;
    } else {                    // Q projection of query_tokens
        const int sid = bid - 384;
        bm = sid & 3; bn = sid >> 2;
        Ag = X2h; Bkg = Wqh; biask = bq; outk = Qlin; hasV = false;
    }
    const int row0 = bm * 256, col0 = bn * 128;

    const int tid = threadIdx.x;
    const int w = tid >> 6, lane = tid & 63;
    const int wr = w >> 1, wc = w & 1;      // 4 M-waves x 2 N-waves
    const int fr = lane & 15, kg = lane >> 4;

    f32x4 acck[4][4], accv[4][4];
#pragma unroll
    for (int m = 0; m < 4; ++m)
#pragma unroll
        for (int n = 0; n < 4; ++n) {
            acck[m][n] = (f32x4){0.f, 0.f, 0.f, 0.f};
            accv[m][n] = (f32x4){0.f, 0.f, 0.f, 0.f};
        }

#define STAGE(sel, kt)                                                           \
    do {                                                                         \
        const int kk = (kt) << 5;                                                \
        _Pragma("unroll")                                                        \
        for (int i = 0; i < 2; ++i) {                                            \
            const int c = i * 512 + tid;                                         \
            const int row = c >> 2, ks = (c & 3) << 3;                           \
            gldh(Ag + (size_t)(row0 + row) * CC + kk + ks, &As[sel][c * 8]);     \
        }                                                                        \
        {                                                                        \
            const int row = tid >> 2, ks = (tid & 3) << 3;                       \
            gldh(Bkg + (size_t)(col0 + row) * CC + kk + ks, &Bks[sel][tid * 8]); \
            gldh(Wvh + (size_t)(col0 + row) * CC + kk + ks, &Bvs[sel][tid * 8]); \
        }                                                                        \
    } while (0)

    STAGE(0, 0);
    int cur = 0;
    const int nk = CC >> 5;    // 24
    for (int kt = 0; kt < nk; ++kt) {
        __syncthreads();
        if (kt + 1 < nk) STAGE(cur ^ 1, kt + 1);
        const _Float16* lA = As[cur];
        const _Float16* lBk = Bks[cur];
        const _Float16* lBv = Bvs[cur];
        f16x8 a[4];
#pragma unroll
        for (int m = 0; m < 4; ++m)
            a[m] = *(const f16x8*)(lA + (wr * 64 + m * 16 + fr) * 32 + kg * 8);
#pragma unroll
        for (int n = 0; n < 4; ++n) {
            f16x8 bkf = *(const f16x8*)(lBk + (wc * 64 + n * 16 + fr) * 32 + kg * 8);
#pragma unroll
            for (int m = 0; m < 4; ++m)
                acck[m][n] = __builtin_amdgcn_mfma_f32_16x16x32_f16(
                    a[m], bkf, acck[m][n], 0, 0, 0);
            f16x8 bvf = *(const f16x8*)(lBv + (wc * 64 + n * 16 + fr) * 32 + kg * 8);
#pragma unroll
            for (int m = 0; m < 4; ++m)
                accv[m][n] = __builtin_amdgcn_mfma_f32_16x16x32_f16(
                    a[m], bvf, accv[m][n], 0, 0, 0);
        }
        cur ^= 1;
    }
#undef STAGE

    {   // K (or Q) epilogue: f16 [row][col]
        float bvv[4];
#pragma unroll
        for (int n = 0; n < 4; ++n)
            bvv[n] = biask[col0 + wc * 64 + n * 16 + fr];
#pragma unroll
        for (int m = 0; m < 4; ++m)
#pragma unroll
            for (int n = 0; n < 4; ++n) {
                const int col = col0 + wc * 64 + n * 16 + fr;
#pragma unroll
                for (int r = 0; r < 4; ++r) {
                    const int row = row0 + wr * 64 + m * 16 + kg * 4 + r;
                    outk[(size_t)row * CC + col] = (_Float16)(acck[m][n][r] + bvv[n]);
                }
            }
    }
    if (hasV) {   // V epilogue: transposed f16 Vth[(b*12+h)*64+d][token]
        const int b = row0 >> 12;
        const int rb = row0 & 4095;
#pragma unroll
        for (int n = 0; n < 4; ++n) {
            const int cg = col0 + wc * 64 + n * 16 + fr;
            const int hh = cg >> 6, d = cg & 63;
            const float bb = bv[cg];
            _Float16* vrow = Vth + ((size_t)((b * HH + hh) * DD + d)) * NN
                             + rb + wr * 64;
#pragma unroll
            for (int m = 0; m < 4; ++m) {
                f16x4 v4;
#pragma unroll
                for (int r = 0; r < 4; ++r)
                    v4[r] = (_Float16)(accv[m][n][r] + bb);
                *(f16x4*)(vrow + m * 16 + kg * 4) = v4;
            }
        }
    }
}

// ---------------------------------------------------------------------------
// LayerNorm over rows of 768, f16 in -> f16 out (Q gets 1/sqrt(D) folded)
// ---------------------------------------------------------------------------
__global__ __launch_bounds__(256) void ln_rows_f16(
    const _Float16* __restrict__ Y, _Float16* __restrict__ outh,
    const float* __restrict__ g, const float* __restrict__ be, const float scale)
{
    const int row = blockIdx.x;
    const _Float16* y = Y + (size_t)row * CC;
    const int tid = threadIdx.x;
    float x0 = (float)y[tid], x1 = (float)y[tid + 256], x2 = (float)y[tid + 512];
    float s = x0 + x1 + x2;
    float q = x0 * x0 + x1 * x1 + x2 * x2;
#pragma unroll
    for (int o = 32; o >= 1; o >>= 1) {
        s += __shfl_xor(s, o, 64);
        q += __shfl_xor(q, o, 64);
    }
    __shared__ float sh_s[4], sh_q[4];
    const int w = tid >> 6;
    if ((tid & 63) == 0) { sh_s[w] = s; sh_q[w] = q; }
    __syncthreads();
    s = sh_s[0] + sh_s[1] + sh_s[2] + sh_s[3];
    q = sh_q[0] + sh_q[1] + sh_q[2] + sh_q[3];
    const float mu  = s * (1.f / 768.f);
    const float var = q * (1.f / 768.f) - mu * mu;
    const float inv = rsqrtf(var + LN_EPSF);
    _Float16* o = outh + (size_t)row * CC;
    o[tid]       = (_Float16)(((x0 - mu) * inv * g[tid]       + be[tid])       * scale);
    o[tid + 256] = (_Float16)(((x1 - mu) * inv * g[tid + 256] + be[tid + 256]) * scale);
    o[tid + 512] = (_Float16)(((x2 - mu) * inv * g[tid + 512] + be[tid + 512]) * scale);
}

// ---------------------------------------------------------------------------
// Attention stage 1: partial softmax stats per (b,h,32 q-rows, 1024-n slice).
// grid = 1536: mt-major (round-8 known-good config).
// Writes stats[((bh*8+mt)*32 + qrow)*8 + ns*2] = (max, sumexp).
// ---------------------------------------------------------------------------
__global__ __launch_bounds__(256, 4) void attn_stats(
    const _Float16* __restrict__ Qh,   // [B][256][768] LN'd, *SCALE
    const _Float16* __restrict__ Kh,   // [B][4096][768] LN'd
    float* __restrict__ stats)
{
    __shared__ __align__(16) unsigned char smem[37888];
    _Float16* Kl = (_Float16*)smem;                    // [2][128][64] 32KB
    _Float16* Ql = (_Float16*)(smem + 32768);          // [32][64]      4KB
    float (*red)[32][2] = (float(*)[32][2])(smem + 36864);  // 1KB

    const int tid = threadIdx.x;
    const int w = tid >> 6, lane = tid & 63;
    const int l5 = lane >> 5, lm = lane & 31;
    const int bid = blockIdx.x;
    const int mt = bid / 192;
    const int rem = bid % 192;
    const int bh = rem >> 2, ns = rem & 3;
    const int h = bh % HH, b = bh / HH;
    const int qr0 = mt * 32;
    const int nb = ns * 1024;

#define STAGEK(sel, c0)                                                         \
    _Pragma("unroll")                                                           \
    for (int i = 0; i < 4; ++i) {                                               \
        const int L = i * 256 + tid;                                            \
        const int n = L >> 3, pos = L & 7;                                      \
        gldh(Kh + (size_t)(b * NN + (c0) + n) * CC + h * DD + ((pos ^ (n & 7)) << 3), \
             &Kl[(sel) * 8192 + (i * 256 + w * 64) * 8]);                       \
    }

    {   // stage Q tile (32 rows x 64 d), swizzled
        const int n = tid >> 3, pos = tid & 7;
        gldh(Qh + (size_t)(b * MM + qr0 + n) * CC + h * DD + ((pos ^ (n & 7)) << 3),
             &Ql[(w * 64) * 8]);
    }
    STAGEK(0, nb);
    __syncthreads();
    f16x8 qf[4];
#pragma unroll
    for (int ks = 0; ks < 4; ++ks)
        qf[ks] = *(const f16x8*)&Ql[lm * 64 + (((ks * 2 + l5) ^ (lm & 7)) << 3)];

    const int nl = w * 32 + lm;

    float mrun = -1e30f, srun = 0.f;
    int cur = 0;
    for (int c = 0; c < 8; ++c) {
        if (c) __syncthreads();
        if (c + 1 < 8) STAGEK(cur ^ 1, nb + (c + 1) * 128);
        const _Float16* Kb = Kl + cur * 8192;
        f32x16 s;
#pragma unroll
        for (int r = 0; r < 16; ++r) s[r] = 0.f;
        __builtin_amdgcn_s_setprio(1);
#pragma unroll
        for (int ks = 0; ks < 4; ++ks) {
            f16x8 kf = *(const f16x8*)&Kb[nl * 64 + (((ks * 2 + l5) ^ (nl & 7)) << 3)];
            s = __builtin_amdgcn_mfma_f32_32x32x16_f16(kf, qf[ks], s, 0, 0, 0);
        }
        __builtin_amdgcn_s_setprio(0);
        float cmax = s[0];
#pragma unroll
        for (int r = 1; r < 16; ++r) cmax = fmaxf(cmax, s[r]);
        cmax = fmaxf(cmax, __shfl_xor(cmax, 32, 64));
        const float nm = fmaxf(mrun, cmax);
        float cs = 0.f;
#pragma unroll
        for (int r = 0; r < 16; ++r) cs += __expf(s[r] - nm);
        cs += __shfl_xor(cs, 32, 64);
        srun = srun * __expf(mrun - nm) + cs;
        mrun = nm;
        cur ^= 1;
    }
    if (lane < 32) { red[w][lane][0] = mrun; red[w][lane][1] = srun; }
    __syncthreads();
    if (w == 0 && lane < 32) {
        float M = -1e30f;
#pragma unroll
        for (int ww = 0; ww < 4; ++ww) M = fmaxf(M, red[ww][lane][0]);
        float S = 0.f;
#pragma unroll
        for (int ww = 0; ww < 4; ++ww) S += red[ww][lane][1] * __expf(red[ww][lane][0] - M);
        float* sp = stats + ((size_t)((bh * 8 + mt) * 32 + lane)) * 8 + ns * 2;
        sp[0] = M; sp[1] = S;
    }
#undef STAGEK
}

// ---------------------------------------------------------------------------
// Attention stage 2 (round-8 structure + full-line NT P store): per
// (b,h,32 q-rows), FULL n range, grid 384. P is packed f16 into LDS (as
// before, for PV); the f32 global P store goes LDS->reg->NT with 4 lanes
// covering each 64B line (full-line streaming write, no L2 pollution).
// ---------------------------------------------------------------------------
__global__ __launch_bounds__(256, 2) void attn_main(
    const _Float16* __restrict__ Qh, const _Float16* __restrict__ Kh,
    const _Float16* __restrict__ Vt,   // [B*H][64][4096]
    const float* __restrict__ stats, const float* __restrict__ qtok,
    float* __restrict__ attn, float* __restrict__ out0)
{
    __shared__ __align__(16) unsigned char smem[77824];
    _Float16* Kl = (_Float16*)smem;                    // [2][128][64] 32KB
    _Float16* Vl = (_Float16*)(smem + 32768);          // [2][64][128] 32KB
    _Float16* Ql = (_Float16*)(smem + 65536);          // [32][64]      4KB
    _Float16* Pl = (_Float16*)(smem + 69632);          // [32][128]     8KB
    float* rbuf = (float*)smem;                        // epilogue 32KB

    const int tid = threadIdx.x;
    const int w = tid >> 6, lane = tid & 63;
    const int l5 = lane >> 5, lm = lane & 31;
    const int bh = blockIdx.x % 48;        // bh-minor: same bh -> same XCD
    const int mt = blockIdx.x / 48;
    const int h = bh % HH, b = bh / HH;
    const int qr0 = mt * 32;

#define STAGEK(sel, c0)                                                         \
    _Pragma("unroll")                                                           \
    for (int i = 0; i < 4; ++i) {                                               \
        const int L = i * 256 + tid;                                            \
        const int n = L >> 3, pos = L & 7;                                      \
        gldh(Kh + (size_t)(b * NN + (c0) + n) * CC + h * DD + ((pos ^ (n & 7)) << 3), \
             &Kl[(sel) * 8192 + (i * 256 + w * 64) * 8]);                       \
    }
#define STAGEV(sel, c0)                                                         \
    _Pragma("unroll")                                                           \
    for (int i = 0; i < 4; ++i) {                                               \
        const int L = i * 256 + tid;                                            \
        const int d = L >> 4, pos = L & 15;                                     \
        const int blk = (pos & 8) | ((pos & 7) ^ (d & 7));                      \
        gldh(Vt + (size_t)(bh * DD + d) * NN + (c0) + blk * 8,                  \
             &Vl[(sel) * 8192 + (i * 256 + w * 64) * 8]);                       \
    }

    // merged global stats for this lane's q-row
    float M, invS;
    {
        const float* sp = stats + ((size_t)((bh * 8 + mt) * 32 + lm)) * 8;
        M = -1e30f;
#pragma unroll
        for (int n2 = 0; n2 < 4; ++n2) M = fmaxf(M, sp[n2 * 2]);
        float S = 0.f;
#pragma unroll
        for (int n2 = 0; n2 < 4; ++n2) S += sp[n2 * 2 + 1] * __expf(sp[n2 * 2] - M);
        invS = 1.f / S;
    }

    {   // stage Q tile
        const int n = tid >> 3, pos = tid & 7;
        gldh(Qh + (size_t)(b * MM + qr0 + n) * CC + h * DD + ((pos ^ (n & 7)) << 3),
             &Ql[(w * 64) * 8]);
    }
    STAGEK(0, 0); STAGEV(0, 0);
    __syncthreads();
    f16x8 qf[4];
#pragma unroll
    for (int ks = 0; ks < 4; ++ks)
        qf[ks] = *(const f16x8*)&Ql[lm * 64 + (((ks * 2 + l5) ^ (lm & 7)) << 3)];

    const int nl = w * 32 + lm;

    f32x16 oacc[2];
#pragma unroll
    for (int dt = 0; dt < 2; ++dt)
#pragma unroll
        for (int r = 0; r < 16; ++r) oacc[dt][r] = 0.f;

    int cur = 0;
    for (int c = 0; c < 32; ++c) {
        if (c) __syncthreads();
        if (c + 1 < 32) { STAGEK(cur ^ 1, (c + 1) * 128); STAGEV(cur ^ 1, (c + 1) * 128); }
        const _Float16* Kb = Kl + cur * 8192;
        const _Float16* Vb = Vl + cur * 8192;
        f32x16 s;
#pragma unroll
        for (int r = 0; r < 16; ++r) s[r] = 0.f;
        __builtin_amdgcn_s_setprio(1);
#pragma unroll
        for (int ks = 0; ks < 4; ++ks) {
            f16x8 kf = *(const f16x8*)&Kb[nl * 64 + (((ks * 2 + l5) ^ (nl & 7)) << 3)];
            s = __builtin_amdgcn_mfma_f32_32x32x16_f16(kf, qf[ks], s, 0, 0, 0);
        }
        __builtin_amdgcn_s_setprio(0);
        // P -> LDS (f16, swizzled) only; global store happens via readback
#pragma unroll
        for (int q = 0; q < 4; ++q) {
            f16x4 ph;
#pragma unroll
            for (int r = 0; r < 4; ++r)
                ph[r] = (_Float16)(__expf(s[q * 4 + r] - M) * invS);
            const int blk16 = w * 4 + q;
            const int pos = (blk16 & 8) | ((blk16 & 7) ^ (lm & 7));
            *(f16x4*)&Pl[lm * 128 + pos * 8 + l5 * 4] = ph;
        }
        __builtin_amdgcn_s_setprio(1);
#pragma unroll
        for (int ks = 0; ks < 2; ++ks) {
            const int blk16 = w * 4 + ks * 2 + l5;
            const int posP = (blk16 & 8) | ((blk16 & 7) ^ (lm & 7));
            f16x8 pf = *(const f16x8*)&Pl[lm * 128 + posP * 8];
#pragma unroll
            for (int dt = 0; dt < 2; ++dt) {
                const int d = dt * 32 + lm;
                const int posV = (blk16 & 8) | ((blk16 & 7) ^ (d & 7));
                f16x8 vf = *(const f16x8*)&Vb[d * 128 + posV * 8];
                oacc[dt] = __builtin_amdgcn_mfma_f32_32x32x16_f16(pf, vf, oacc[dt], 0, 0, 0);
            }
        }
        __builtin_amdgcn_s_setprio(0);
        // Full-line NT writeback of this wave's own n-window (all 32 rows):
        // 4 lanes x 16B cover each 64B line within one instruction.
#pragma unroll
        for (int p = 0; p < 4; ++p) {
            const int pr = p >> 1, nh = p & 1;
            const int row = pr * 16 + (lane >> 2);       // 0..31
            const int k = lane & 3;
            const int nn = nh * 16 + k * 4;              // within wave's 32-n
            const int j = w * 4 + (nn >> 3);
            const int swz = (j & 8) | ((j & 7) ^ (row & 7));
            f16x4 pv4 = *(const f16x4*)&Pl[row * 128 + swz * 8 + (nn & 7)];
            f32x4 o4;
            o4[0] = (float)pv4[0]; o4[1] = (float)pv4[1];
            o4[2] = (float)pv4[2]; o4[3] = (float)pv4[3];
            __builtin_nontemporal_store(o4,
                (f32x4*)(attn + ((size_t)(bh * MM + qr0 + row)) * NN
                         + c * 128 + w * 32 + nn));
        }
        cur ^= 1;
    }

    // epilogue: cross-wave reduce + residual
    __syncthreads();
#pragma unroll
    for (int dt = 0; dt < 2; ++dt)
#pragma unroll
        for (int r = 0; r < 16; ++r) {
            const int mrow = (r & 3) + 8 * (r >> 2) + 4 * l5;
            rbuf[w * 2048 + mrow * 64 + dt * 32 + lm] = oacc[dt][r];
        }
    __syncthreads();
    {
        const int m = tid >> 3, d0 = (tid & 7) * 8;
        const size_t obase = (size_t)(b * MM + qr0 + m) * CC + h * DD + d0;
        f32x4 v0, v1;
#pragma unroll
        for (int j = 0; j < 4; ++j) {
            const int idx = m * 64 + d0 + j;
            v0[j] = rbuf[idx] + rbuf[2048 + idx] + rbuf[4096 + idx] + rbuf[6144 + idx];
        }
#pragma unroll
        for (int j = 0; j < 4; ++j) {
            const int idx = m * 64 + d0 + 4 + j;
            v1[j] = rbuf[idx] + rbuf[2048 + idx] + rbuf[4096 + idx] + rbuf[6144 + idx];
        }
        float4 q0 = *(const float4*)(qtok + obase);
        float4 q1 = *(const float4*)(qtok + obase + 4);
        v0[0] += q0.x; v0[1] += q0.y; v0[2] += q0.z; v0[3] += q0.w;
        v1[0] += q1.x; v1[1] += q1.y; v1[2] += q1.z; v1[3] += q1.w;
        *(f32x4*)(out0 + obase) = v0;
        *(f32x4*)(out0 + obase + 4) = v1;
    }
#undef STAGEK
#undef STAGEV
}

extern "C" void kernel_launch(void* const* d_in, const int* in_sizes, int n_in,
                              void* d_out, int out_size, void* d_ws, size_t ws_size,
                              hipStream_t stream) {
    (void)in_sizes; (void)n_in; (void)out_size; (void)ws_size;
    const float* input_tokens = (const float*)d_in[0];
    const float* query_tokens = (const float*)d_in[1];
    const float* Wq   = (const float*)d_in[2];
    const float* bq   = (const float*)d_in[3];
    const float* Wk   = (const float*)d_in[4];
    const float* bk   = (const float*)d_in[5];
    const float* Wv   = (const float*)d_in[6];
    const float* bv   = (const float*)d_in[7];
    const float* gq   = (const float*)d_in[8];
    const float* bqln = (const float*)d_in[9];
    const float* gk   = (const float*)d_in[10];
    const float* bkln = (const float*)d_in[11];

    float* out0 = (float*)d_out;
    float* attn = out0 + (size_t)BB * MM * CC;

    _Float16* hptr = (_Float16*)d_ws;
    _Float16* Klin = hptr;                              // [B*N][C]
    _Float16* Qlin = Klin + (size_t)BB * NN * CC;       // [B*M][C]
    _Float16* Xh   = Qlin + (size_t)BB * MM * CC;       // [B*N][C]
    _Float16* X2h  = Xh   + (size_t)BB * NN * CC;       // [B*M][C]
    _Float16* Wkh  = X2h  + (size_t)BB * MM * CC;       // [C][C]
    _Float16* Wqh  = Wkh  + (size_t)CC * CC;
    _Float16* Wvh  = Wqh  + (size_t)CC * CC;
    _Float16* Kh   = Wvh  + (size_t)CC * CC;            // post-LN K
    _Float16* Qh   = Kh   + (size_t)BB * NN * CC;       // post-LN Q
    _Float16* Vt   = Qh   + (size_t)BB * MM * CC;       // [48][64][4096]
    float* stats   = (float*)(Vt + (size_t)BB * HH * DD * NN);  // [12288][4][2]

    // --- all f32->f16 conversions in one dispatch ---
    conv_all<<<2048, 256, 0, stream>>>(
        input_tokens, Xh, (long long)BB * NN * CC,
        query_tokens, X2h, (long long)BB * MM * CC,
        Wk, Wkh, (long long)CC * CC,
        Wq, Wqh, (long long)CC * CC,
        Wv, Wvh, (long long)CC * CC);

    // --- K+V fused projection (+Q blocks), 256x128 tile, 512 thr ---
    proj_kv_f16<<<408, 512, 0, stream>>>(Xh, X2h, Wkh, Wqh, Wvh,
                                         bk, bq, bv, Klin, Qlin, Vt);

    // --- LayerNorm -> f16 (scale folded into Q) ---
    ln_rows_f16<<<BB * NN, 256, 0, stream>>>(Klin, Kh, gk, bkln, 1.0f);
    ln_rows_f16<<<BB * MM, 256, 0, stream>>>(Qlin, Qh, gq, bqln, SCALEF);

    // --- attention: high-occupancy stats sweep, then full-range main ---
    attn_stats<<<1536, 256, 0, stream>>>(Qh, Kh, stats);
    attn_main<<<384, 256, 0, stream>>>(Qh, Kh, Vt, stats, query_tokens, attn, out0);
}

// Round 15
// 187.618 us; speedup vs baseline: 1.0157x; 1.0157x over previous
//
#include <hip/hip_runtime.h>
#include <math.h>

#define BB 4
#define NN 4096
#define MM 256
#define CC 768
#define HH 12
#define DD 64
#define SCALEF 0.125f
#define LN_EPSF 1e-5f

typedef __attribute__((ext_vector_type(4))) float f32x4;
typedef __attribute__((ext_vector_type(16))) float f32x16;
typedef __attribute__((ext_vector_type(8))) _Float16 f16x8;
typedef __attribute__((ext_vector_type(4))) _Float16 f16x4;

// ---------------------------------------------------------------------------
// helpers
// ---------------------------------------------------------------------------
__device__ __forceinline__ void gldh(const _Float16* g, _Float16* l) {
    __builtin_amdgcn_global_load_lds(
        (const __attribute__((address_space(1))) void*)g,
        (__attribute__((address_space(3))) void*)l, 16, 0, 0);
}

// ---------------------------------------------------------------------------
// merged f32 -> f16 conversion over 5 segments, grid-stride, 8-wide.
// ---------------------------------------------------------------------------
__global__ __launch_bounds__(256) void conv_all(
    const float* __restrict__ x0, _Float16* __restrict__ y0, long long n0,
    const float* __restrict__ x1, _Float16* __restrict__ y1, long long n1,
    const float* __restrict__ x2, _Float16* __restrict__ y2, long long n2,
    const float* __restrict__ x3, _Float16* __restrict__ y3, long long n3,
    const float* __restrict__ x4, _Float16* __restrict__ y4, long long n4)
{
    long long i = ((long long)blockIdx.x * 256 + threadIdx.x) * 8;
    const long long total = n0 + n1 + n2 + n3 + n4;
    const long long stride = (long long)gridDim.x * 256 * 8;
    for (; i < total; i += stride) {
        const float* x; _Float16* y; long long off = i;
        if (off < n0) { x = x0; y = y0; }
        else if ((off -= n0) < n1) { x = x1; y = y1; }
        else if ((off -= n1) < n2) { x = x2; y = y2; }
        else if ((off -= n2) < n3) { x = x3; y = y3; }
        else { off -= n3; x = x4; y = y4; }
        float4 a = *(const float4*)(x + off);
        float4 b = *(const float4*)(x + off + 4);
        f16x8 o;
        o[0] = (_Float16)a.x; o[1] = (_Float16)a.y;
        o[2] = (_Float16)a.z; o[3] = (_Float16)a.w;
        o[4] = (_Float16)b.x; o[5] = (_Float16)b.y;
        o[6] = (_Float16)b.z; o[7] = (_Float16)b.w;
        *(f16x8*)(y + off) = o;
    }
}

// ---------------------------------------------------------------------------
// KV-fused fp16 MFMA GEMM (round-13 config): 128x128 tile, 256 threads.
// One block computes BOTH Wk and Wv projections of the same 128-row A panel.
// Q-proj blocks ride the same path (V result discarded). K path writes f16
// [row][col]; V path writes f16 transposed [b*H+h][d][token].
// ---------------------------------------------------------------------------
__global__ __launch_bounds__(256) void proj_kv_f16(
    const _Float16* __restrict__ Xh,   // [16384][768]
    const _Float16* __restrict__ X2h,  // [1024][768]
    const _Float16* __restrict__ Wkh, const _Float16* __restrict__ Wqh,
    const _Float16* __restrict__ Wvh,  // each [768][768]
    const float* __restrict__ bk, const float* __restrict__ bq,
    const float* __restrict__ bv,
    _Float16* __restrict__ Klin, _Float16* __restrict__ Qlin,
    _Float16* __restrict__ Vth)        // [48][64][4096]
{
    __shared__ _Float16 As[2][4096];
    __shared__ _Float16 Bks[2][4096];
    __shared__ _Float16 Bvs[2][4096];

    const int bid = blockIdx.x;
    const _Float16* Ag; const _Float16* Bkg;
    const float* biask; _Float16* outk;
    bool hasV;
    int bm, bn;
    if (bid < 768) {            // K+V projections of input_tokens
        bm = bid & 127; bn = bid >> 7;     // stride-128 row-sharing -> same XCD
        Ag = Xh; Bkg = Wkh; biask = bk; outk = Klin; hasV = true;
    } else {                    // Q projection of query_tokens
        const int sid = bid - 768;
        bm = sid & 7; bn = sid >> 3;
        Ag = X2h; Bkg = Wqh; biask = bq; outk = Qlin; hasV = false;
    }
    const int row0 = bm * 128, col0 = bn * 128;

    const int tid = threadIdx.x;
    const int w = tid >> 6, lane = tid & 63;
    const int wr = w >> 1, wc = w & 1;
    const int fr = lane & 15, kg = lane >> 4;

    f32x4 acck[4][4], accv[4][4];
#pragma unroll
    for (int m = 0; m < 4; ++m)
#pragma unroll
        for (int n = 0; n < 4; ++n) {
            acck[m][n] = (f32x4){0.f, 0.f, 0.f, 0.f};
            accv[m][n] = (f32x4){0.f, 0.f, 0.f, 0.f};
        }

#define STAGE(sel, kt)                                                           \
    do {                                                                         \
        const int kk = (kt) << 5;                                                \
        _Pragma("unroll")                                                        \
        for (int i = 0; i < 2; ++i) {                                            \
            const int cbase = (i * 4 + w) * 64;                                  \
            const int c = cbase + lane;                                          \
            const int row = c >> 2, ks = (c & 3) << 3;                           \
            gldh(Ag  + (size_t)(row0 + row) * CC + kk + ks, &As[sel][cbase * 8]);\
            gldh(Bkg + (size_t)(col0 + row) * CC + kk + ks, &Bks[sel][cbase * 8]);\
            gldh(Wvh + (size_t)(col0 + row) * CC + kk + ks, &Bvs[sel][cbase * 8]);\
        }                                                                        \
    } while (0)

    STAGE(0, 0);
    int cur = 0;
    const int nk = CC >> 5;    // 24
    for (int kt = 0; kt < nk; ++kt) {
        __syncthreads();
        if (kt + 1 < nk) STAGE(cur ^ 1, kt + 1);
        const _Float16* lA = As[cur];
        const _Float16* lBk = Bks[cur];
        const _Float16* lBv = Bvs[cur];
        f16x8 a[4];
#pragma unroll
        for (int m = 0; m < 4; ++m)
            a[m] = *(const f16x8*)(lA + (wr * 64 + m * 16 + fr) * 32 + kg * 8);
#pragma unroll
        for (int n = 0; n < 4; ++n) {
            f16x8 bkf = *(const f16x8*)(lBk + (wc * 64 + n * 16 + fr) * 32 + kg * 8);
            __builtin_amdgcn_s_setprio(1);
#pragma unroll
            for (int m = 0; m < 4; ++m)
                acck[m][n] = __builtin_amdgcn_mfma_f32_16x16x32_f16(
                    a[m], bkf, acck[m][n], 0, 0, 0);
            __builtin_amdgcn_s_setprio(0);
            f16x8 bvf = *(const f16x8*)(lBv + (wc * 64 + n * 16 + fr) * 32 + kg * 8);
            __builtin_amdgcn_s_setprio(1);
#pragma unroll
            for (int m = 0; m < 4; ++m)
                accv[m][n] = __builtin_amdgcn_mfma_f32_16x16x32_f16(
                    a[m], bvf, accv[m][n], 0, 0, 0);
            __builtin_amdgcn_s_setprio(0);
        }
        cur ^= 1;
    }
#undef STAGE

    {   // K (or Q) epilogue: f16 [row][col]
        float bvv[4];
#pragma unroll
        for (int n = 0; n < 4; ++n)
            bvv[n] = biask[col0 + wc * 64 + n * 16 + fr];
#pragma unroll
        for (int m = 0; m < 4; ++m)
#pragma unroll
            for (int n = 0; n < 4; ++n) {
                const int col = col0 + wc * 64 + n * 16 + fr;
#pragma unroll
                for (int r = 0; r < 4; ++r) {
                    const int row = row0 + wr * 64 + m * 16 + kg * 4 + r;
                    outk[(size_t)row * CC + col] = (_Float16)(acck[m][n][r] + bvv[n]);
                }
            }
    }
    if (hasV) {   // V epilogue: transposed f16 Vth[(b*12+h)*64+d][token]
        const int b = row0 >> 12;
        const int rb = row0 & 4095;
#pragma unroll
        for (int n = 0; n < 4; ++n) {
            const int cg = col0 + wc * 64 + n * 16 + fr;
            const int hh = cg >> 6, d = cg & 63;
            const float bb = bv[cg];
            _Float16* vrow = Vth + ((size_t)((b * HH + hh) * DD + d)) * NN + rb + wr * 64;
#pragma unroll
            for (int m = 0; m < 4; ++m) {
                f16x4 v4;
#pragma unroll
                for (int r = 0; r < 4; ++r)
                    v4[r] = (_Float16)(accv[m][n][r] + bb);
                *(f16x4*)(vrow + m * 16 + kg * 4) = v4;
            }
        }
    }
}

// ---------------------------------------------------------------------------
// LayerNorm over rows of 768, f16 in -> f16 out (Q gets 1/sqrt(D) folded)
// ---------------------------------------------------------------------------
__global__ __launch_bounds__(256) void ln_rows_f16(
    const _Float16* __restrict__ Y, _Float16* __restrict__ outh,
    const float* __restrict__ g, const float* __restrict__ be, const float scale)
{
    const int row = blockIdx.x;
    const _Float16* y = Y + (size_t)row * CC;
    const int tid = threadIdx.x;
    float x0 = (float)y[tid], x1 = (float)y[tid + 256], x2 = (float)y[tid + 512];
    float s = x0 + x1 + x2;
    float q = x0 * x0 + x1 * x1 + x2 * x2;
#pragma unroll
    for (int o = 32; o >= 1; o >>= 1) {
        s += __shfl_xor(s, o, 64);
        q += __shfl_xor(q, o, 64);
    }
    __shared__ float sh_s[4], sh_q[4];
    const int w = tid >> 6;
    if ((tid & 63) == 0) { sh_s[w] = s; sh_q[w] = q; }
    __syncthreads();
    s = sh_s[0] + sh_s[1] + sh_s[2] + sh_s[3];
    q = sh_q[0] + sh_q[1] + sh_q[2] + sh_q[3];
    const float mu  = s * (1.f / 768.f);
    const float var = q * (1.f / 768.f) - mu * mu;
    const float inv = rsqrtf(var + LN_EPSF);
    _Float16* o = outh + (size_t)row * CC;
    o[tid]       = (_Float16)(((x0 - mu) * inv * g[tid]       + be[tid])       * scale);
    o[tid + 256] = (_Float16)(((x1 - mu) * inv * g[tid + 256] + be[tid + 256]) * scale);
    o[tid + 512] = (_Float16)(((x2 - mu) * inv * g[tid + 512] + be[tid + 512]) * scale);
}

// ---------------------------------------------------------------------------
// Attention stage 1: partial softmax stats per (b,h,32 q-rows, 1024-n slice).
// grid = 1536: mt-major (round-8 known-good config).
// Writes stats[((bh*8+mt)*32 + qrow)*8 + ns*2] = (max, sumexp).
// ---------------------------------------------------------------------------
__global__ __launch_bounds__(256, 4) void attn_stats(
    const _Float16* __restrict__ Qh,   // [B][256][768] LN'd, *SCALE
    const _Float16* __restrict__ Kh,   // [B][4096][768] LN'd
    float* __restrict__ stats)
{
    __shared__ __align__(16) unsigned char smem[37888];
    _Float16* Kl = (_Float16*)smem;                    // [2][128][64] 32KB
    _Float16* Ql = (_Float16*)(smem + 32768);          // [32][64]      4KB
    float (*red)[32][2] = (float(*)[32][2])(smem + 36864);  // 1KB

    const int tid = threadIdx.x;
    const int w = tid >> 6, lane = tid & 63;
    const int l5 = lane >> 5, lm = lane & 31;
    const int bid = blockIdx.x;
    const int mt = bid / 192;
    const int rem = bid % 192;
    const int bh = rem >> 2, ns = rem & 3;
    const int h = bh % HH, b = bh / HH;
    const int qr0 = mt * 32;
    const int nb = ns * 1024;

#define STAGEK(sel, c0)                                                         \
    _Pragma("unroll")                                                           \
    for (int i = 0; i < 4; ++i) {                                               \
        const int L = i * 256 + tid;                                            \
        const int n = L >> 3, pos = L & 7;                                      \
        gldh(Kh + (size_t)(b * NN + (c0) + n) * CC + h * DD + ((pos ^ (n & 7)) << 3), \
             &Kl[(sel) * 8192 + (i * 256 + w * 64) * 8]);                       \
    }

    {   // stage Q tile (32 rows x 64 d), swizzled
        const int n = tid >> 3, pos = tid & 7;
        gldh(Qh + (size_t)(b * MM + qr0 + n) * CC + h * DD + ((pos ^ (n & 7)) << 3),
             &Ql[(w * 64) * 8]);
    }
    STAGEK(0, nb);
    __syncthreads();
    f16x8 qf[4];
#pragma unroll
    for (int ks = 0; ks < 4; ++ks)
        qf[ks] = *(const f16x8*)&Ql[lm * 64 + (((ks * 2 + l5) ^ (lm & 7)) << 3)];

    const int nl = w * 32 + lm;

    float mrun = -1e30f, srun = 0.f;
    int cur = 0;
    for (int c = 0; c < 8; ++c) {
        if (c) __syncthreads();
        if (c + 1 < 8) STAGEK(cur ^ 1, nb + (c + 1) * 128);
        const _Float16* Kb = Kl + cur * 8192;
        f32x16 s;
#pragma unroll
        for (int r = 0; r < 16; ++r) s[r] = 0.f;
        __builtin_amdgcn_s_setprio(1);
#pragma unroll
        for (int ks = 0; ks < 4; ++ks) {
            f16x8 kf = *(const f16x8*)&Kb[nl * 64 + (((ks * 2 + l5) ^ (nl & 7)) << 3)];
            s = __builtin_amdgcn_mfma_f32_32x32x16_f16(kf, qf[ks], s, 0, 0, 0);
        }
        __builtin_amdgcn_s_setprio(0);
        float cmax = s[0];
#pragma unroll
        for (int r = 1; r < 16; ++r) cmax = fmaxf(cmax, s[r]);
        cmax = fmaxf(cmax, __shfl_xor(cmax, 32, 64));
        const float nm = fmaxf(mrun, cmax);
        float cs = 0.f;
#pragma unroll
        for (int r = 0; r < 16; ++r) cs += __expf(s[r] - nm);
        cs += __shfl_xor(cs, 32, 64);
        srun = srun * __expf(mrun - nm) + cs;
        mrun = nm;
        cur ^= 1;
    }
    if (lane < 32) { red[w][lane][0] = mrun; red[w][lane][1] = srun; }
    __syncthreads();
    if (w == 0 && lane < 32) {
        float M = -1e30f;
#pragma unroll
        for (int ww = 0; ww < 4; ++ww) M = fmaxf(M, red[ww][lane][0]);
        float S = 0.f;
#pragma unroll
        for (int ww = 0; ww < 4; ++ww) S += red[ww][lane][1] * __expf(red[ww][lane][0] - M);
        float* sp = stats + ((size_t)((bh * 8 + mt) * 32 + lane)) * 8 + ns * 2;
        sp[0] = M; sp[1] = S;
    }
#undef STAGEK
}

// ---------------------------------------------------------------------------
// Attention stage 2: round-13 structure (full-line NT P store) + counted
// vmcnt barrier. With NT stores the old __syncthreads (vmcnt(0)) serialized
// on 4 NT-store HBM acks per chunk; issue order is [8 staging loads (old),
// 4 NT stores (new)], so s_waitcnt vmcnt(4)+s_barrier waits exactly the
// staging loads and lets NT stores drain under the next chunk's compute.
// ---------------------------------------------------------------------------
__global__ __launch_bounds__(256, 2) void attn_main(
    const _Float16* __restrict__ Qh, const _Float16* __restrict__ Kh,
    const _Float16* __restrict__ Vt,   // [B*H][64][4096]
    const float* __restrict__ stats, const float* __restrict__ qtok,
    float* __restrict__ attn, float* __restrict__ out0)
{
    __shared__ __align__(16) unsigned char smem[77824];
    _Float16* Kl = (_Float16*)smem;                    // [2][128][64] 32KB
    _Float16* Vl = (_Float16*)(smem + 32768);          // [2][64][128] 32KB
    _Float16* Ql = (_Float16*)(smem + 65536);          // [32][64]      4KB
    _Float16* Pl = (_Float16*)(smem + 69632);          // [32][128]     8KB
    float* rbuf = (float*)smem;                        // epilogue 32KB

    const int tid = threadIdx.x;
    const int w = tid >> 6, lane = tid & 63;
    const int l5 = lane >> 5, lm = lane & 31;
    const int bh = blockIdx.x % 48;        // bh-minor: same bh -> same XCD
    const int mt = blockIdx.x / 48;
    const int h = bh % HH, b = bh / HH;
    const int qr0 = mt * 32;

#define STAGEK(sel, c0)                                                         \
    _Pragma("unroll")                                                           \
    for (int i = 0; i < 4; ++i) {                                               \
        const int L = i * 256 + tid;                                            \
        const int n = L >> 3, pos = L & 7;                                      \
        gldh(Kh + (size_t)(b * NN + (c0) + n) * CC + h * DD + ((pos ^ (n & 7)) << 3), \
             &Kl[(sel) * 8192 + (i * 256 + w * 64) * 8]);                       \
    }
#define STAGEV(sel, c0)                                                         \
    _Pragma("unroll")                                                           \
    for (int i = 0; i < 4; ++i) {                                               \
        const int L = i * 256 + tid;                                            \
        const int d = L >> 4, pos = L & 15;                                     \
        const int blk = (pos & 8) | ((pos & 7) ^ (d & 7));                      \
        gldh(Vt + (size_t)(bh * DD + d) * NN + (c0) + blk * 8,                  \
             &Vl[(sel) * 8192 + (i * 256 + w * 64) * 8]);                       \
    }

    // merged global stats for this lane's q-row
    float M, invS;
    {
        const float* sp = stats + ((size_t)((bh * 8 + mt) * 32 + lm)) * 8;
        M = -1e30f;
#pragma unroll
        for (int n2 = 0; n2 < 4; ++n2) M = fmaxf(M, sp[n2 * 2]);
        float S = 0.f;
#pragma unroll
        for (int n2 = 0; n2 < 4; ++n2) S += sp[n2 * 2 + 1] * __expf(sp[n2 * 2] - M);
        invS = 1.f / S;
    }

    {   // stage Q tile
        const int n = tid >> 3, pos = tid & 7;
        gldh(Qh + (size_t)(b * MM + qr0 + n) * CC + h * DD + ((pos ^ (n & 7)) << 3),
             &Ql[(w * 64) * 8]);
    }
    STAGEK(0, 0); STAGEV(0, 0);
    __syncthreads();
    f16x8 qf[4];
#pragma unroll
    for (int ks = 0; ks < 4; ++ks)
        qf[ks] = *(const f16x8*)&Ql[lm * 64 + (((ks * 2 + l5) ^ (lm & 7)) << 3)];

    const int nl = w * 32 + lm;

    f32x16 oacc[2];
#pragma unroll
    for (int dt = 0; dt < 2; ++dt)
#pragma unroll
        for (int r = 0; r < 16; ++r) oacc[dt][r] = 0.f;

    int cur = 0;
    for (int c = 0; c < 32; ++c) {
        if (c) {
            // wait the 8 staging loads (oldest); leave <=4 NT stores in flight
            asm volatile("s_waitcnt vmcnt(4)" ::: "memory");
            __builtin_amdgcn_s_barrier();
            __builtin_amdgcn_sched_barrier(0);
        }
        if (c + 1 < 32) { STAGEK(cur ^ 1, (c + 1) * 128); STAGEV(cur ^ 1, (c + 1) * 128); }
        __builtin_amdgcn_sched_barrier(0);   // pin: loads issue before NT stores
        const _Float16* Kb = Kl + cur * 8192;
        const _Float16* Vb = Vl + cur * 8192;
        f32x16 s;
#pragma unroll
        for (int r = 0; r < 16; ++r) s[r] = 0.f;
        __builtin_amdgcn_s_setprio(1);
#pragma unroll
        for (int ks = 0; ks < 4; ++ks) {
            f16x8 kf = *(const f16x8*)&Kb[nl * 64 + (((ks * 2 + l5) ^ (nl & 7)) << 3)];
            s = __builtin_amdgcn_mfma_f32_32x32x16_f16(kf, qf[ks], s, 0, 0, 0);
        }
        __builtin_amdgcn_s_setprio(0);
        // P -> LDS (f16, swizzled) only; global store happens via readback
#pragma unroll
        for (int q = 0; q < 4; ++q) {
            f16x4 ph;
#pragma unroll
            for (int r = 0; r < 4; ++r)
                ph[r] = (_Float16)(__expf(s[q * 4 + r] - M) * invS);
            const int blk16 = w * 4 + q;
            const int pos = (blk16 & 8) | ((blk16 & 7) ^ (lm & 7));
            *(f16x4*)&Pl[lm * 128 + pos * 8 + l5 * 4] = ph;
        }
        __builtin_amdgcn_s_setprio(1);
#pragma unroll
        for (int ks = 0; ks < 2; ++ks) {
            const int blk16 = w * 4 + ks * 2 + l5;
            const int posP = (blk16 & 8) | ((blk16 & 7) ^ (lm & 7));
            f16x8 pf = *(const f16x8*)&Pl[lm * 128 + posP * 8];
#pragma unroll
            for (int dt = 0; dt < 2; ++dt) {
                const int d = dt * 32 + lm;
                const int posV = (blk16 & 8) | ((blk16 & 7) ^ (d & 7));
                f16x8 vf = *(const f16x8*)&Vb[d * 128 + posV * 8];
                oacc[dt] = __builtin_amdgcn_mfma_f32_32x32x16_f16(pf, vf, oacc[dt], 0, 0, 0);
            }
        }
        __builtin_amdgcn_s_setprio(0);
        // Full-line NT writeback of this wave's own n-window (all 32 rows):
        // 4 lanes x 16B cover each 64B line within one instruction.
#pragma unroll
        for (int p = 0; p < 4; ++p) {
            const int pr = p >> 1, nh = p & 1;
            const int row = pr * 16 + (lane >> 2);       // 0..31
            const int k = lane & 3;
            const int nn = nh * 16 + k * 4;              // within wave's 32-n
            const int j = w * 4 + (nn >> 3);
            const int swz = (j & 8) | ((j & 7) ^ (row & 7));
            f16x4 pv4 = *(const f16x4*)&Pl[row * 128 + swz * 8 + (nn & 7)];
            f32x4 o4;
            o4[0] = (float)pv4[0]; o4[1] = (float)pv4[1];
            o4[2] = (float)pv4[2]; o4[3] = (float)pv4[3];
            __builtin_nontemporal_store(o4,
                (f32x4*)(attn + ((size_t)(bh * MM + qr0 + row)) * NN
                         + c * 128 + w * 32 + nn));
        }
        cur ^= 1;
    }

    // epilogue: cross-wave reduce + residual
    __syncthreads();
#pragma unroll
    for (int dt = 0; dt < 2; ++dt)
#pragma unroll
        for (int r = 0; r < 16; ++r) {
            const int mrow = (r & 3) + 8 * (r >> 2) + 4 * l5;
            rbuf[w * 2048 + mrow * 64 + dt * 32 + lm] = oacc[dt][r];
        }
    __syncthreads();
    {
        const int m = tid >> 3, d0 = (tid & 7) * 8;
        const size_t obase = (size_t)(b * MM + qr0 + m) * CC + h * DD + d0;
        f32x4 v0, v1;
#pragma unroll
        for (int j = 0; j < 4; ++j) {
            const int idx = m * 64 + d0 + j;
            v0[j] = rbuf[idx] + rbuf[2048 + idx] + rbuf[4096 + idx] + rbuf[6144 + idx];
        }
#pragma unroll
        for (int j = 0; j < 4; ++j) {
            const int idx = m * 64 + d0 + 4 + j;
            v1[j] = rbuf[idx] + rbuf[2048 + idx] + rbuf[4096 + idx] + rbuf[6144 + idx];
        }
        float4 q0 = *(const float4*)(qtok + obase);
        float4 q1 = *(const float4*)(qtok + obase + 4);
        v0[0] += q0.x; v0[1] += q0.y; v0[2] += q0.z; v0[3] += q0.w;
        v1[0] += q1.x; v1[1] += q1.y; v1[2] += q1.z; v1[3] += q1.w;
        *(f32x4*)(out0 + obase) = v0;
        *(f32x4*)(out0 + obase + 4) = v1;
    }
#undef STAGEK
#undef STAGEV
}

extern "C" void kernel_launch(void* const* d_in, const int* in_sizes, int n_in,
                              void* d_out, int out_size, void* d_ws, size_t ws_size,
                              hipStream_t stream) {
    (void)in_sizes; (void)n_in; (void)out_size; (void)ws_size;
    const float* input_tokens = (const float*)d_in[0];
    const float* query_tokens = (const float*)d_in[1];
    const float* Wq   = (const float*)d_in[2];
    const float* bq   = (const float*)d_in[3];
    const float* Wk   = (const float*)d_in[4];
    const float* bk   = (const float*)d_in[5];
    const float* Wv   = (const float*)d_in[6];
    const float* bv   = (const float*)d_in[7];
    const float* gq   = (const float*)d_in[8];
    const float* bqln = (const float*)d_in[9];
    const float* gk   = (const float*)d_in[10];
    const float* bkln = (const float*)d_in[11];

    float* out0 = (float*)d_out;
    float* attn = out0 + (size_t)BB * MM * CC;

    _Float16* hptr = (_Float16*)d_ws;
    _Float16* Klin = hptr;                              // [B*N][C]
    _Float16* Qlin = Klin + (size_t)BB * NN * CC;       // [B*M][C]
    _Float16* Xh   = Qlin + (size_t)BB * MM * CC;       // [B*N][C]
    _Float16* X2h  = Xh   + (size_t)BB * NN * CC;       // [B*M][C]
    _Float16* Wkh  = X2h  + (size_t)BB * MM * CC;       // [C][C]
    _Float16* Wqh  = Wkh  + (size_t)CC * CC;
    _Float16* Wvh  = Wqh  + (size_t)CC * CC;
    _Float16* Kh   = Wvh  + (size_t)CC * CC;            // post-LN K
    _Float16* Qh   = Kh   + (size_t)BB * NN * CC;       // post-LN Q
    _Float16* Vt   = Qh   + (size_t)BB * MM * CC;       // [48][64][4096]
    float* stats   = (float*)(Vt + (size_t)BB * HH * DD * NN);  // [12288][4][2]

    // --- all f32->f16 conversions in one dispatch ---
    conv_all<<<2048, 256, 0, stream>>>(
        input_tokens, Xh, (long long)BB * NN * CC,
        query_tokens, X2h, (long long)BB * MM * CC,
        Wk, Wkh, (long long)CC * CC,
        Wq, Wqh, (long long)CC * CC,
        Wv, Wvh, (long long)CC * CC);

    // --- K+V fused projection (+Q blocks) in one MFMA dispatch ---
    proj_kv_f16<<<816, 256, 0, stream>>>(Xh, X2h, Wkh, Wqh, Wvh,
                                         bk, bq, bv, Klin, Qlin, Vt);

    // --- LayerNorm -> f16 (scale folded into Q) ---
    ln_rows_f16<<<BB * NN, 256, 0, stream>>>(Klin, Kh, gk, bkln, 1.0f);
    ln_rows_f16<<<BB * MM, 256, 0, stream>>>(Qlin, Qh, gq, bqln, SCALEF);

    // --- attention: high-occupancy stats sweep, then full-range main ---
    attn_stats<<<1536, 256, 0, stream>>>(Qh, Kh, stats);
    attn_main<<<384, 256, 0, stream>>>(Qh, Kh, Vt, stats, query_tokens, attn, out0);
}

// Round 16
// 186.497 us; speedup vs baseline: 1.0218x; 1.0060x over previous
//
#include <hip/hip_runtime.h>
#include <math.h>

#define BB 4
#define NN 4096
#define MM 256
#define CC 768
#define HH 12
#define DD 64
#define SCALEF 0.125f
#define LN_EPSF 1e-5f

typedef __attribute__((ext_vector_type(4))) float f32x4;
typedef __attribute__((ext_vector_type(16))) float f32x16;
typedef __attribute__((ext_vector_type(8))) _Float16 f16x8;
typedef __attribute__((ext_vector_type(4))) _Float16 f16x4;

// ---------------------------------------------------------------------------
// helpers
// ---------------------------------------------------------------------------
__device__ __forceinline__ void gldh(const _Float16* g, _Float16* l) {
    __builtin_amdgcn_global_load_lds(
        (const __attribute__((address_space(1))) void*)g,
        (__attribute__((address_space(3))) void*)l, 16, 0, 0);
}

// ---------------------------------------------------------------------------
// merged f32 -> f16 conversion over 5 segments, grid-stride, 8-wide.
// ---------------------------------------------------------------------------
__global__ __launch_bounds__(256) void conv_all(
    const float* __restrict__ x0, _Float16* __restrict__ y0, long long n0,
    const float* __restrict__ x1, _Float16* __restrict__ y1, long long n1,
    const float* __restrict__ x2, _Float16* __restrict__ y2, long long n2,
    const float* __restrict__ x3, _Float16* __restrict__ y3, long long n3,
    const float* __restrict__ x4, _Float16* __restrict__ y4, long long n4)
{
    long long i = ((long long)blockIdx.x * 256 + threadIdx.x) * 8;
    const long long total = n0 + n1 + n2 + n3 + n4;
    const long long stride = (long long)gridDim.x * 256 * 8;
    for (; i < total; i += stride) {
        const float* x; _Float16* y; long long off = i;
        if (off < n0) { x = x0; y = y0; }
        else if ((off -= n0) < n1) { x = x1; y = y1; }
        else if ((off -= n1) < n2) { x = x2; y = y2; }
        else if ((off -= n2) < n3) { x = x3; y = y3; }
        else { off -= n3; x = x4; y = y4; }
        float4 a = *(const float4*)(x + off);
        float4 b = *(const float4*)(x + off + 4);
        f16x8 o;
        o[0] = (_Float16)a.x; o[1] = (_Float16)a.y;
        o[2] = (_Float16)a.z; o[3] = (_Float16)a.w;
        o[4] = (_Float16)b.x; o[5] = (_Float16)b.y;
        o[6] = (_Float16)b.z; o[7] = (_Float16)b.w;
        *(f16x8*)(y + off) = o;
    }
}

// ---------------------------------------------------------------------------
// KV-fused fp16 MFMA GEMM, 128x128 tile, 256 threads, TRIPLE-buffered LDS
// with counted-vmcnt barriers (T4): prefetch 2 K-steps ahead, per iteration
// wait s_waitcnt vmcnt(6) (leaves the newest tile's 6 loads in flight) +
// raw s_barrier. Loads span barriers -> no vmcnt(0) drain per K-step.
// One block computes BOTH Wk and Wv projections of the same 128-row A panel.
// Q-proj blocks ride the same path (V result discarded).
// ---------------------------------------------------------------------------
__global__ __launch_bounds__(256) void proj_kv_f16(
    const _Float16* __restrict__ Xh,   // [16384][768]
    const _Float16* __restrict__ X2h,  // [1024][768]
    const _Float16* __restrict__ Wkh, const _Float16* __restrict__ Wqh,
    const _Float16* __restrict__ Wvh,  // each [768][768]
    const float* __restrict__ bk, const float* __restrict__ bq,
    const float* __restrict__ bv,
    _Float16* __restrict__ Klin, _Float16* __restrict__ Qlin,
    _Float16* __restrict__ Vth)        // [48][64][4096]
{
    __shared__ _Float16 As[3][4096];   // 24 KB
    __shared__ _Float16 Bks[3][4096];  // 24 KB
    __shared__ _Float16 Bvs[3][4096];  // 24 KB

    const int bid = blockIdx.x;
    const _Float16* Ag; const _Float16* Bkg;
    const float* biask; _Float16* outk;
    bool hasV;
    int bm, bn;
    if (bid < 768) {            // K+V projections of input_tokens
        bm = bid & 127; bn = bid >> 7;     // stride-128 row-sharing -> same XCD
        Ag = Xh; Bkg = Wkh; biask = bk; outk = Klin; hasV = true;
    } else {                    // Q projection of query_tokens
        const int sid = bid - 768;
        bm = sid & 7; bn = sid >> 3;
        Ag = X2h; Bkg = Wqh; biask = bq; outk = Qlin; hasV = false;
    }
    const int row0 = bm * 128, col0 = bn * 128;

    const int tid = threadIdx.x;
    const int w = tid >> 6, lane = tid & 63;
    const int wr = w >> 1, wc = w & 1;
    const int fr = lane & 15, kg = lane >> 4;

    f32x4 acck[4][4], accv[4][4];
#pragma unroll
    for (int m = 0; m < 4; ++m)
#pragma unroll
        for (int n = 0; n < 4; ++n) {
            acck[m][n] = (f32x4){0.f, 0.f, 0.f, 0.f};
            accv[m][n] = (f32x4){0.f, 0.f, 0.f, 0.f};
        }

#define STAGE(sel, kt)                                                           \
    do {                                                                         \
        const int kk = (kt) << 5;                                                \
        _Pragma("unroll")                                                        \
        for (int i = 0; i < 2; ++i) {                                            \
            const int cbase = (i * 4 + w) * 64;                                  \
            const int c = cbase + lane;                                          \
            const int row = c >> 2, ks = (c & 3) << 3;                           \
            gldh(Ag  + (size_t)(row0 + row) * CC + kk + ks, &As[sel][cbase * 8]);\
            gldh(Bkg + (size_t)(col0 + row) * CC + kk + ks, &Bks[sel][cbase * 8]);\
            gldh(Wvh + (size_t)(col0 + row) * CC + kk + ks, &Bvs[sel][cbase * 8]);\
        }                                                                        \
    } while (0)

    STAGE(0, 0);
    STAGE(1, 1);
    const int nk = CC >> 5;    // 24
    for (int kt = 0; kt < nk; ++kt) {
        // per-wave: >=12 loads in flight at steady state; vmcnt(6) retires
        // everything except the newest tile's 6 -> current tile ready.
        if (kt + 1 < nk) asm volatile("s_waitcnt vmcnt(6)" ::: "memory");
        else             asm volatile("s_waitcnt vmcnt(0)" ::: "memory");
        __builtin_amdgcn_s_barrier();
        __builtin_amdgcn_sched_barrier(0);
        if (kt + 2 < nk) STAGE((kt + 2) % 3, kt + 2);
        const int cur = kt % 3;
        const _Float16* lA = As[cur];
        const _Float16* lBk = Bks[cur];
        const _Float16* lBv = Bvs[cur];
        f16x8 a[4];
#pragma unroll
        for (int m = 0; m < 4; ++m)
            a[m] = *(const f16x8*)(lA + (wr * 64 + m * 16 + fr) * 32 + kg * 8);
#pragma unroll
        for (int n = 0; n < 4; ++n) {
            f16x8 bkf = *(const f16x8*)(lBk + (wc * 64 + n * 16 + fr) * 32 + kg * 8);
            __builtin_amdgcn_s_setprio(1);
#pragma unroll
            for (int m = 0; m < 4; ++m)
                acck[m][n] = __builtin_amdgcn_mfma_f32_16x16x32_f16(
                    a[m], bkf, acck[m][n], 0, 0, 0);
            __builtin_amdgcn_s_setprio(0);
            f16x8 bvf = *(const f16x8*)(lBv + (wc * 64 + n * 16 + fr) * 32 + kg * 8);
            __builtin_amdgcn_s_setprio(1);
#pragma unroll
            for (int m = 0; m < 4; ++m)
                accv[m][n] = __builtin_amdgcn_mfma_f32_16x16x32_f16(
                    a[m], bvf, accv[m][n], 0, 0, 0);
            __builtin_amdgcn_s_setprio(0);
        }
    }
#undef STAGE

    {   // K (or Q) epilogue: f16 [row][col]
        float bvv[4];
#pragma unroll
        for (int n = 0; n < 4; ++n)
            bvv[n] = biask[col0 + wc * 64 + n * 16 + fr];
#pragma unroll
        for (int m = 0; m < 4; ++m)
#pragma unroll
            for (int n = 0; n < 4; ++n) {
                const int col = col0 + wc * 64 + n * 16 + fr;
#pragma unroll
                for (int r = 0; r < 4; ++r) {
                    const int row = row0 + wr * 64 + m * 16 + kg * 4 + r;
                    outk[(size_t)row * CC + col] = (_Float16)(acck[m][n][r] + bvv[n]);
                }
            }
    }
    if (hasV) {   // V epilogue: transposed f16 Vth[(b*12+h)*64+d][token]
        const int b = row0 >> 12;
        const int rb = row0 & 4095;
#pragma unroll
        for (int n = 0; n < 4; ++n) {
            const int cg = col0 + wc * 64 + n * 16 + fr;
            const int hh = cg >> 6, d = cg & 63;
            const float bb = bv[cg];
            _Float16* vrow = Vth + ((size_t)((b * HH + hh) * DD + d)) * NN + rb + wr * 64;
#pragma unroll
            for (int m = 0; m < 4; ++m) {
                f16x4 v4;
#pragma unroll
                for (int r = 0; r < 4; ++r)
                    v4[r] = (_Float16)(accv[m][n][r] + bb);
                *(f16x4*)(vrow + m * 16 + kg * 4) = v4;
            }
        }
    }
}

// ---------------------------------------------------------------------------
// Merged LayerNorm: rows [0, BB*NN) = K (scale 1), rows [BB*NN, +BB*MM) = Q
// (scale 1/sqrt(D)). f16 in -> f16 out. One dispatch for both.
// ---------------------------------------------------------------------------
__global__ __launch_bounds__(256) void ln_rows_f16(
    const _Float16* __restrict__ Klin, const _Float16* __restrict__ Qlin,
    _Float16* __restrict__ Kh, _Float16* __restrict__ Qh,
    const float* __restrict__ gk, const float* __restrict__ bkln,
    const float* __restrict__ gq, const float* __restrict__ bqln)
{
    int row = blockIdx.x;
    const _Float16* y; _Float16* o;
    const float* g; const float* be; float scale;
    if (row < BB * NN) {
        y = Klin + (size_t)row * CC; o = Kh + (size_t)row * CC;
        g = gk; be = bkln; scale = 1.0f;
    } else {
        row -= BB * NN;
        y = Qlin + (size_t)row * CC; o = Qh + (size_t)row * CC;
        g = gq; be = bqln; scale = SCALEF;
    }
    const int tid = threadIdx.x;
    float x0 = (float)y[tid], x1 = (float)y[tid + 256], x2 = (float)y[tid + 512];
    float s = x0 + x1 + x2;
    float q = x0 * x0 + x1 * x1 + x2 * x2;
#pragma unroll
    for (int o2 = 32; o2 >= 1; o2 >>= 1) {
        s += __shfl_xor(s, o2, 64);
        q += __shfl_xor(q, o2, 64);
    }
    __shared__ float sh_s[4], sh_q[4];
    const int w = tid >> 6;
    if ((tid & 63) == 0) { sh_s[w] = s; sh_q[w] = q; }
    __syncthreads();
    s = sh_s[0] + sh_s[1] + sh_s[2] + sh_s[3];
    q = sh_q[0] + sh_q[1] + sh_q[2] + sh_q[3];
    const float mu  = s * (1.f / 768.f);
    const float var = q * (1.f / 768.f) - mu * mu;
    const float inv = rsqrtf(var + LN_EPSF);
    o[tid]       = (_Float16)(((x0 - mu) * inv * g[tid]       + be[tid])       * scale);
    o[tid + 256] = (_Float16)(((x1 - mu) * inv * g[tid + 256] + be[tid + 256]) * scale);
    o[tid + 512] = (_Float16)(((x2 - mu) * inv * g[tid + 512] + be[tid + 512]) * scale);
}

// ---------------------------------------------------------------------------
// Attention stage 1: partial softmax stats per (b,h,32 q-rows, 1024-n slice).
// grid = 1536: mt-major (round-8 known-good config).
// Writes stats[((bh*8+mt)*32 + qrow)*8 + ns*2] = (max, sumexp).
// ---------------------------------------------------------------------------
__global__ __launch_bounds__(256, 4) void attn_stats(
    const _Float16* __restrict__ Qh,   // [B][256][768] LN'd, *SCALE
    const _Float16* __restrict__ Kh,   // [B][4096][768] LN'd
    float* __restrict__ stats)
{
    __shared__ __align__(16) unsigned char smem[37888];
    _Float16* Kl = (_Float16*)smem;                    // [2][128][64] 32KB
    _Float16* Ql = (_Float16*)(smem + 32768);          // [32][64]      4KB
    float (*red)[32][2] = (float(*)[32][2])(smem + 36864);  // 1KB

    const int tid = threadIdx.x;
    const int w = tid >> 6, lane = tid & 63;
    const int l5 = lane >> 5, lm = lane & 31;
    const int bid = blockIdx.x;
    const int mt = bid / 192;
    const int rem = bid % 192;
    const int bh = rem >> 2, ns = rem & 3;
    const int h = bh % HH, b = bh / HH;
    const int qr0 = mt * 32;
    const int nb = ns * 1024;

#define STAGEK(sel, c0)                                                         \
    _Pragma("unroll")                                                           \
    for (int i = 0; i < 4; ++i) {                                               \
        const int L = i * 256 + tid;                                            \
        const int n = L >> 3, pos = L & 7;                                      \
        gldh(Kh + (size_t)(b * NN + (c0) + n) * CC + h * DD + ((pos ^ (n & 7)) << 3), \
             &Kl[(sel) * 8192 + (i * 256 + w * 64) * 8]);                       \
    }

    {   // stage Q tile (32 rows x 64 d), swizzled
        const int n = tid >> 3, pos = tid & 7;
        gldh(Qh + (size_t)(b * MM + qr0 + n) * CC + h * DD + ((pos ^ (n & 7)) << 3),
             &Ql[(w * 64) * 8]);
    }
    STAGEK(0, nb);
    __syncthreads();
    f16x8 qf[4];
#pragma unroll
    for (int ks = 0; ks < 4; ++ks)
        qf[ks] = *(const f16x8*)&Ql[lm * 64 + (((ks * 2 + l5) ^ (lm & 7)) << 3)];

    const int nl = w * 32 + lm;

    float mrun = -1e30f, srun = 0.f;
    int cur = 0;
    for (int c = 0; c < 8; ++c) {
        if (c) __syncthreads();
        if (c + 1 < 8) STAGEK(cur ^ 1, nb + (c + 1) * 128);
        const _Float16* Kb = Kl + cur * 8192;
        f32x16 s;
#pragma unroll
        for (int r = 0; r < 16; ++r) s[r] = 0.f;
        __builtin_amdgcn_s_setprio(1);
#pragma unroll
        for (int ks = 0; ks < 4; ++ks) {
            f16x8 kf = *(const f16x8*)&Kb[nl * 64 + (((ks * 2 + l5) ^ (nl & 7)) << 3)];
            s = __builtin_amdgcn_mfma_f32_32x32x16_f16(kf, qf[ks], s, 0, 0, 0);
        }
        __builtin_amdgcn_s_setprio(0);
        float cmax = s[0];
#pragma unroll
        for (int r = 1; r < 16; ++r) cmax = fmaxf(cmax, s[r]);
        cmax = fmaxf(cmax, __shfl_xor(cmax, 32, 64));
        const float nm = fmaxf(mrun, cmax);
        float cs = 0.f;
#pragma unroll
        for (int r = 0; r < 16; ++r) cs += __expf(s[r] - nm);
        cs += __shfl_xor(cs, 32, 64);
        srun = srun * __expf(mrun - nm) + cs;
        mrun = nm;
        cur ^= 1;
    }
    if (lane < 32) { red[w][lane][0] = mrun; red[w][lane][1] = srun; }
    __syncthreads();
    if (w == 0 && lane < 32) {
        float M = -1e30f;
#pragma unroll
        for (int ww = 0; ww < 4; ++ww) M = fmaxf(M, red[ww][lane][0]);
        float S = 0.f;
#pragma unroll
        for (int ww = 0; ww < 4; ++ww) S += red[ww][lane][1] * __expf(red[ww][lane][0] - M);
        float* sp = stats + ((size_t)((bh * 8 + mt) * 32 + lane)) * 8 + ns * 2;
        sp[0] = M; sp[1] = S;
    }
#undef STAGEK
}

// ---------------------------------------------------------------------------
// Attention stage 2: round-15 structure (full-line NT P store + counted
// vmcnt barrier). Per (b,h,32 q-rows), FULL n range, grid 384.
// ---------------------------------------------------------------------------
__global__ __launch_bounds__(256, 2) void attn_main(
    const _Float16* __restrict__ Qh, const _Float16* __restrict__ Kh,
    const _Float16* __restrict__ Vt,   // [B*H][64][4096]
    const float* __restrict__ stats, const float* __restrict__ qtok,
    float* __restrict__ attn, float* __restrict__ out0)
{
    __shared__ __align__(16) unsigned char smem[77824];
    _Float16* Kl = (_Float16*)smem;                    // [2][128][64] 32KB
    _Float16* Vl = (_Float16*)(smem + 32768);          // [2][64][128] 32KB
    _Float16* Ql = (_Float16*)(smem + 65536);          // [32][64]      4KB
    _Float16* Pl = (_Float16*)(smem + 69632);          // [32][128]     8KB
    float* rbuf = (float*)smem;                        // epilogue 32KB

    const int tid = threadIdx.x;
    const int w = tid >> 6, lane = tid & 63;
    const int l5 = lane >> 5, lm = lane & 31;
    const int bh = blockIdx.x % 48;        // bh-minor: same bh -> same XCD
    const int mt = blockIdx.x / 48;
    const int h = bh % HH, b = bh / HH;
    const int qr0 = mt * 32;

#define STAGEK(sel, c0)                                                         \
    _Pragma("unroll")                                                           \
    for (int i = 0; i < 4; ++i) {                                               \
        const int L = i * 256 + tid;                                            \
        const int n = L >> 3, pos = L & 7;                                      \
        gldh(Kh + (size_t)(b * NN + (c0) + n) * CC + h * DD + ((pos ^ (n & 7)) << 3), \
             &Kl[(sel) * 8192 + (i * 256 + w * 64) * 8]);                       \
    }
#define STAGEV(sel, c0)                                                         \
    _Pragma("unroll")                                                           \
    for (int i = 0; i < 4; ++i) {                                               \
        const int L = i * 256 + tid;                                            \
        const int d = L >> 4, pos = L & 15;                                     \
        const int blk = (pos & 8) | ((pos & 7) ^ (d & 7));                      \
        gldh(Vt + (size_t)(bh * DD + d) * NN + (c0) + blk * 8,                  \
             &Vl[(sel) * 8192 + (i * 256 + w * 64) * 8]);                       \
    }

    // merged global stats for this lane's q-row
    float M, invS;
    {
        const float* sp = stats + ((size_t)((bh * 8 + mt) * 32 + lm)) * 8;
        M = -1e30f;
#pragma unroll
        for (int n2 = 0; n2 < 4; ++n2) M = fmaxf(M, sp[n2 * 2]);
        float S = 0.f;
#pragma unroll
        for (int n2 = 0; n2 < 4; ++n2) S += sp[n2 * 2 + 1] * __expf(sp[n2 * 2] - M);
        invS = 1.f / S;
    }

    {   // stage Q tile
        const int n = tid >> 3, pos = tid & 7;
        gldh(Qh + (size_t)(b * MM + qr0 + n) * CC + h * DD + ((pos ^ (n & 7)) << 3),
             &Ql[(w * 64) * 8]);
    }
    STAGEK(0, 0); STAGEV(0, 0);
    __syncthreads();
    f16x8 qf[4];
#pragma unroll
    for (int ks = 0; ks < 4; ++ks)
        qf[ks] = *(const f16x8*)&Ql[lm * 64 + (((ks * 2 + l5) ^ (lm & 7)) << 3)];

    const int nl = w * 32 + lm;

    f32x16 oacc[2];
#pragma unroll
    for (int dt = 0; dt < 2; ++dt)
#pragma unroll
        for (int r = 0; r < 16; ++r) oacc[dt][r] = 0.f;

    int cur = 0;
    for (int c = 0; c < 32; ++c) {
        if (c) {
            // wait the 8 staging loads (oldest); leave <=4 NT stores in flight
            asm volatile("s_waitcnt vmcnt(4)" ::: "memory");
            __builtin_amdgcn_s_barrier();
            __builtin_amdgcn_sched_barrier(0);
        }
        if (c + 1 < 32) { STAGEK(cur ^ 1, (c + 1) * 128); STAGEV(cur ^ 1, (c + 1) * 128); }
        __builtin_amdgcn_sched_barrier(0);   // pin: loads issue before NT stores
        const _Float16* Kb = Kl + cur * 8192;
        const _Float16* Vb = Vl + cur * 8192;
        f32x16 s;
#pragma unroll
        for (int r = 0; r < 16; ++r) s[r] = 0.f;
        __builtin_amdgcn_s_setprio(1);
#pragma unroll
        for (int ks = 0; ks < 4; ++ks) {
            f16x8 kf = *(const f16x8*)&Kb[nl * 64 + (((ks * 2 + l5) ^ (nl & 7)) << 3)];
            s = __builtin_amdgcn_mfma_f32_32x32x16_f16(kf, qf[ks], s, 0, 0, 0);
        }
        __builtin_amdgcn_s_setprio(0);
        // P -> LDS (f16, swizzled) only; global store happens via readback
#pragma unroll
        for (int q = 0; q < 4; ++q) {
            f16x4 ph;
#pragma unroll
            for (int r = 0; r < 4; ++r)
                ph[r] = (_Float16)(__expf(s[q * 4 + r] - M) * invS);
            const int blk16 = w * 4 + q;
            const int pos = (blk16 & 8) | ((blk16 & 7) ^ (lm & 7));
            *(f16x4*)&Pl[lm * 128 + pos * 8 + l5 * 4] = ph;
        }
        __builtin_amdgcn_s_setprio(1);
#pragma unroll
        for (int ks = 0; ks < 2; ++ks) {
            const int blk16 = w * 4 + ks * 2 + l5;
            const int posP = (blk16 & 8) | ((blk16 & 7) ^ (lm & 7));
            f16x8 pf = *(const f16x8*)&Pl[lm * 128 + posP * 8];
#pragma unroll
            for (int dt = 0; dt < 2; ++dt) {
                const int d = dt * 32 + lm;
                const int posV = (blk16 & 8) | ((blk16 & 7) ^ (d & 7));
                f16x8 vf = *(const f16x8*)&Vb[d * 128 + posV * 8];
                oacc[dt] = __builtin_amdgcn_mfma_f32_32x32x16_f16(pf, vf, oacc[dt], 0, 0, 0);
            }
        }
        __builtin_amdgcn_s_setprio(0);
        // Full-line NT writeback of this wave's own n-window (all 32 rows):
        // 4 lanes x 16B cover each 64B line within one instruction.
#pragma unroll
        for (int p = 0; p < 4; ++p) {
            const int pr = p >> 1, nh = p & 1;
            const int row = pr * 16 + (lane >> 2);       // 0..31
            const int k = lane & 3;
            const int nn = nh * 16 + k * 4;              // within wave's 32-n
            const int j = w * 4 + (nn >> 3);
            const int swz = (j & 8) | ((j & 7) ^ (row & 7));
            f16x4 pv4 = *(const f16x4*)&Pl[row * 128 + swz * 8 + (nn & 7)];
            f32x4 o4;
            o4[0] = (float)pv4[0]; o4[1] = (float)pv4[1];
            o4[2] = (float)pv4[2]; o4[3] = (float)pv4[3];
            __builtin_nontemporal_store(o4,
                (f32x4*)(attn + ((size_t)(bh * MM + qr0 + row)) * NN
                         + c * 128 + w * 32 + nn));
        }
        cur ^= 1;
    }

    // epilogue: cross-wave reduce + residual
    __syncthreads();
#pragma unroll
    for (int dt = 0; dt < 2; ++dt)
#pragma unroll
        for (int r = 0; r < 16; ++r) {
            const int mrow = (r & 3) + 8 * (r >> 2) + 4 * l5;
            rbuf[w * 2048 + mrow * 64 + dt * 32 + lm] = oacc[dt][r];
        }
    __syncthreads();
    {
        const int m = tid >> 3, d0 = (tid & 7) * 8;
        const size_t obase = (size_t)(b * MM + qr0 + m) * CC + h * DD + d0;
        f32x4 v0, v1;
#pragma unroll
        for (int j = 0; j < 4; ++j) {
            const int idx = m * 64 + d0 + j;
            v0[j] = rbuf[idx] + rbuf[2048 + idx] + rbuf[4096 + idx] + rbuf[6144 + idx];
        }
#pragma unroll
        for (int j = 0; j < 4; ++j) {
            const int idx = m * 64 + d0 + 4 + j;
            v1[j] = rbuf[idx] + rbuf[2048 + idx] + rbuf[4096 + idx] + rbuf[6144 + idx];
        }
        float4 q0 = *(const float4*)(qtok + obase);
        float4 q1 = *(const float4*)(qtok + obase + 4);
        v0[0] += q0.x; v0[1] += q0.y; v0[2] += q0.z; v0[3] += q0.w;
        v1[0] += q1.x; v1[1] += q1.y; v1[2] += q1.z; v1[3] += q1.w;
        *(f32x4*)(out0 + obase) = v0;
        *(f32x4*)(out0 + obase + 4) = v1;
    }
#undef STAGEK
#undef STAGEV
}

extern "C" void kernel_launch(void* const* d_in, const int* in_sizes, int n_in,
                              void* d_out, int out_size, void* d_ws, size_t ws_size,
                              hipStream_t stream) {
    (void)in_sizes; (void)n_in; (void)out_size; (void)ws_size;
    const float* input_tokens = (const float*)d_in[0];
    const float* query_tokens = (const float*)d_in[1];
    const float* Wq   = (const float*)d_in[2];
    const float* bq   = (const float*)d_in[3];
    const float* Wk   = (const float*)d_in[4];
    const float* bk   = (const float*)d_in[5];
    const float* Wv   = (const float*)d_in[6];
    const float* bv   = (const float*)d_in[7];
    const float* gq   = (const float*)d_in[8];
    const float* bqln = (const float*)d_in[9];
    const float* gk   = (const float*)d_in[10];
    const float* bkln = (const float*)d_in[11];

    float* out0 = (float*)d_out;
    float* attn = out0 + (size_t)BB * MM * CC;

    _Float16* hptr = (_Float16*)d_ws;
    _Float16* Klin = hptr;                              // [B*N][C]
    _Float16* Qlin = Klin + (size_t)BB * NN * CC;       // [B*M][C]
    _Float16* Xh   = Qlin + (size_t)BB * MM * CC;       // [B*N][C]
    _Float16* X2h  = Xh   + (size_t)BB * NN * CC;       // [B*M][C]
    _Float16* Wkh  = X2h  + (size_t)BB * MM * CC;       // [C][C]
    _Float16* Wqh  = Wkh  + (size_t)CC * CC;
    _Float16* Wvh  = Wqh  + (size_t)CC * CC;
    _Float16* Kh   = Wvh  + (size_t)CC * CC;            // post-LN K
    _Float16* Qh   = Kh   + (size_t)BB * NN * CC;       // post-LN Q
    _Float16* Vt   = Qh   + (size_t)BB * MM * CC;       // [48][64][4096]
    float* stats   = (float*)(Vt + (size_t)BB * HH * DD * NN);  // [12288][4][2]

    // --- all f32->f16 conversions in one dispatch ---
    conv_all<<<2048, 256, 0, stream>>>(
        input_tokens, Xh, (long long)BB * NN * CC,
        query_tokens, X2h, (long long)BB * MM * CC,
        Wk, Wkh, (long long)CC * CC,
        Wq, Wqh, (long long)CC * CC,
        Wv, Wvh, (long long)CC * CC);

    // --- K+V fused projection (+Q blocks), triple-buffered counted-vmcnt ---
    proj_kv_f16<<<816, 256, 0, stream>>>(Xh, X2h, Wkh, Wqh, Wvh,
                                         bk, bq, bv, Klin, Qlin, Vt);

    // --- merged LayerNorm (K rows then Q rows) -> f16 ---
    ln_rows_f16<<<BB * NN + BB * MM, 256, 0, stream>>>(Klin, Qlin, Kh, Qh,
                                                       gk, bkln, gq, bqln);

    // --- attention: high-occupancy stats sweep, then full-range main ---
    attn_stats<<<1536, 256, 0, stream>>>(Qh, Kh, stats);
    attn_main<<<384, 256, 0, stream>>>(Qh, Kh, Vt, stats, query_tokens, attn, out0);
}

// Round 17
// 184.813 us; speedup vs baseline: 1.0311x; 1.0091x over previous
//
#include <hip/hip_runtime.h>
#include <math.h>

#define BB 4
#define NN 4096
#define MM 256
#define CC 768
#define HH 12
#define DD 64
#define SCALEF 0.125f
#define LN_EPSF 1e-5f

typedef __attribute__((ext_vector_type(4))) float f32x4;
typedef __attribute__((ext_vector_type(16))) float f32x16;
typedef __attribute__((ext_vector_type(8))) _Float16 f16x8;
typedef __attribute__((ext_vector_type(4))) _Float16 f16x4;

// ---------------------------------------------------------------------------
// helpers
// ---------------------------------------------------------------------------
__device__ __forceinline__ void gldh(const _Float16* g, _Float16* l) {
    __builtin_amdgcn_global_load_lds(
        (const __attribute__((address_space(1))) void*)g,
        (__attribute__((address_space(3))) void*)l, 16, 0, 0);
}

// ---------------------------------------------------------------------------
// f32 -> f16 conversion for the 3 weight matrices only (X converts in-proj).
// ---------------------------------------------------------------------------
__global__ __launch_bounds__(256) void conv_w(
    const float* __restrict__ x0, _Float16* __restrict__ y0,
    const float* __restrict__ x1, _Float16* __restrict__ y1,
    const float* __restrict__ x2, _Float16* __restrict__ y2)
{
    const long long seg = (long long)CC * CC;
    long long i = ((long long)blockIdx.x * 256 + threadIdx.x) * 8;
    const long long stride = (long long)gridDim.x * 256 * 8;
    for (; i < 3 * seg; i += stride) {
        const float* x; _Float16* y; long long off = i;
        if (off < seg) { x = x0; y = y0; }
        else if ((off -= seg) < seg) { x = x1; y = y1; }
        else { off -= seg; x = x2; y = y2; }
        float4 a = *(const float4*)(x + off);
        float4 b = *(const float4*)(x + off + 4);
        f16x8 o;
        o[0] = (_Float16)a.x; o[1] = (_Float16)a.y;
        o[2] = (_Float16)a.z; o[3] = (_Float16)a.w;
        o[4] = (_Float16)b.x; o[5] = (_Float16)b.y;
        o[6] = (_Float16)b.z; o[7] = (_Float16)b.w;
        *(f16x8*)(y + off) = o;
    }
}

// ---------------------------------------------------------------------------
// KV-fused fp16 MFMA GEMM, 128x128 tile, 256 threads, double-buffered.
// A operand is read DIRECTLY FROM f32 input (reg-staged: float4 loads issued
// early, cvt+ds_write after the MFMA block -> T14 latency hiding; removes the
// whole X f32->f16 conv pass). B operands (weights) stay f16 via gldh.
// One block computes BOTH Wk and Wv projections of the same 128-row A panel.
// Q-proj blocks (bid>=768) ride the same path (V result discarded).
// ---------------------------------------------------------------------------
__global__ __launch_bounds__(256) void proj_kv_f16(
    const float* __restrict__ Xf,      // [16384][768] f32 (input_tokens)
    const float* __restrict__ X2f,     // [1024][768]  f32 (query_tokens)
    const _Float16* __restrict__ Wkh, const _Float16* __restrict__ Wqh,
    const _Float16* __restrict__ Wvh,  // each [768][768]
    const float* __restrict__ bk, const float* __restrict__ bq,
    const float* __restrict__ bv,
    _Float16* __restrict__ Klin, _Float16* __restrict__ Qlin,
    _Float16* __restrict__ Vth)        // [48][64][4096]
{
    __shared__ _Float16 As[2][4096];
    __shared__ _Float16 Bks[2][4096];
    __shared__ _Float16 Bvs[2][4096];

    const int bid = blockIdx.x;
    const float* Af; const _Float16* Bkg;
    const float* biask; _Float16* outk;
    bool hasV;
    int bm, bn;
    if (bid < 768) {            // K+V projections of input_tokens
        bm = bid & 127; bn = bid >> 7;     // stride-128 row-sharing -> same XCD
        Af = Xf; Bkg = Wkh; biask = bk; outk = Klin; hasV = true;
    } else {                    // Q projection of query_tokens
        const int sid = bid - 768;
        bm = sid & 7; bn = sid >> 3;
        Af = X2f; Bkg = Wqh; biask = bq; outk = Qlin; hasV = false;
    }
    const int row0 = bm * 128, col0 = bn * 128;

    const int tid = threadIdx.x;
    const int w = tid >> 6, lane = tid & 63;
    const int wr = w >> 1, wc = w & 1;
    const int fr = lane & 15, kg = lane >> 4;

    // A reg-staging geometry: thread t covers row = t>>1, cols (t&1)*16..+15
    const int arow = tid >> 1, acol = (tid & 1) * 16;
    const float* abase = Af + (size_t)(row0 + arow) * CC + acol;

    f32x4 acck[4][4], accv[4][4];
#pragma unroll
    for (int m = 0; m < 4; ++m)
#pragma unroll
        for (int n = 0; n < 4; ++n) {
            acck[m][n] = (f32x4){0.f, 0.f, 0.f, 0.f};
            accv[m][n] = (f32x4){0.f, 0.f, 0.f, 0.f};
        }

    float4 a0, a1, a2, a3;   // in-flight A f32 tile

#define LOADA(kt)                                                                \
    do {                                                                         \
        const float* s_ = abase + ((kt) << 5);                                   \
        a0 = *(const float4*)(s_);      a1 = *(const float4*)(s_ + 4);           \
        a2 = *(const float4*)(s_ + 8);  a3 = *(const float4*)(s_ + 12);          \
    } while (0)

#define WRITEA(sel)                                                              \
    do {                                                                         \
        f16x8 h0_, h1_;                                                          \
        h0_[0] = (_Float16)a0.x; h0_[1] = (_Float16)a0.y;                        \
        h0_[2] = (_Float16)a0.z; h0_[3] = (_Float16)a0.w;                        \
        h0_[4] = (_Float16)a1.x; h0_[5] = (_Float16)a1.y;                        \
        h0_[6] = (_Float16)a1.z; h0_[7] = (_Float16)a1.w;                        \
        h1_[0] = (_Float16)a2.x; h1_[1] = (_Float16)a2.y;                        \
        h1_[2] = (_Float16)a2.z; h1_[3] = (_Float16)a2.w;                        \
        h1_[4] = (_Float16)a3.x; h1_[5] = (_Float16)a3.y;                        \
        h1_[6] = (_Float16)a3.z; h1_[7] = (_Float16)a3.w;                        \
        _Float16* d_ = &As[sel][arow * 32 + acol];                               \
        *(f16x8*)d_ = h0_;                                                       \
        *(f16x8*)(d_ + 8) = h1_;                                                 \
    } while (0)

#define STAGEB(sel, kt)                                                          \
    do {                                                                         \
        const int kk = (kt) << 5;                                                \
        _Pragma("unroll")                                                        \
        for (int i = 0; i < 2; ++i) {                                            \
            const int cbase = (i * 4 + w) * 64;                                  \
            const int c = cbase + lane;                                          \
            const int row = c >> 2, ks = (c & 3) << 3;                           \
            gldh(Bkg + (size_t)(col0 + row) * CC + kk + ks, &Bks[sel][cbase * 8]);\
            gldh(Wvh + (size_t)(col0 + row) * CC + kk + ks, &Bvs[sel][cbase * 8]);\
        }                                                                        \
    } while (0)

    // prologue: stage tile 0
    LOADA(0);
    STAGEB(0, 0);
    WRITEA(0);                 // compiler inserts vmcnt wait for a0..a3
    const int nk = CC >> 5;    // 24
    for (int kt = 0; kt < nk; ++kt) {
        __syncthreads();       // buf cur ready (gldh B + ds_write A drained)
        const int cur = kt & 1, nxt = cur ^ 1;
        if (kt + 1 < nk) { LOADA(kt + 1); STAGEB(nxt, kt + 1); }
        const _Float16* lA = As[cur];
        const _Float16* lBk = Bks[cur];
        const _Float16* lBv = Bvs[cur];
        f16x8 a[4];
#pragma unroll
        for (int m = 0; m < 4; ++m)
            a[m] = *(const f16x8*)(lA + (wr * 64 + m * 16 + fr) * 32 + kg * 8);
#pragma unroll
        for (int n = 0; n < 4; ++n) {
            f16x8 bkf = *(const f16x8*)(lBk + (wc * 64 + n * 16 + fr) * 32 + kg * 8);
            __builtin_amdgcn_s_setprio(1);
#pragma unroll
            for (int m = 0; m < 4; ++m)
                acck[m][n] = __builtin_amdgcn_mfma_f32_16x16x32_f16(
                    a[m], bkf, acck[m][n], 0, 0, 0);
            __builtin_amdgcn_s_setprio(0);
            f16x8 bvf = *(const f16x8*)(lBv + (wc * 64 + n * 16 + fr) * 32 + kg * 8);
            __builtin_amdgcn_s_setprio(1);
#pragma unroll
            for (int m = 0; m < 4; ++m)
                accv[m][n] = __builtin_amdgcn_mfma_f32_16x16x32_f16(
                    a[m], bvf, accv[m][n], 0, 0, 0);
            __builtin_amdgcn_s_setprio(0);
        }
        if (kt + 1 < nk) WRITEA(nxt);   // cvt+ds_write after compute (T14)
    }
#undef LOADA
#undef WRITEA
#undef STAGEB

    {   // K (or Q) epilogue: f16 [row][col]
        float bvv[4];
#pragma unroll
        for (int n = 0; n < 4; ++n)
            bvv[n] = biask[col0 + wc * 64 + n * 16 + fr];
#pragma unroll
        for (int m = 0; m < 4; ++m)
#pragma unroll
            for (int n = 0; n < 4; ++n) {
                const int col = col0 + wc * 64 + n * 16 + fr;
#pragma unroll
                for (int r = 0; r < 4; ++r) {
                    const int row = row0 + wr * 64 + m * 16 + kg * 4 + r;
                    outk[(size_t)row * CC + col] = (_Float16)(acck[m][n][r] + bvv[n]);
                }
            }
    }
    if (hasV) {   // V epilogue: transposed f16 Vth[(b*12+h)*64+d][token]
        const int b = row0 >> 12;
        const int rb = row0 & 4095;
#pragma unroll
        for (int n = 0; n < 4; ++n) {
            const int cg = col0 + wc * 64 + n * 16 + fr;
            const int hh = cg >> 6, d = cg & 63;
            const float bb = bv[cg];
            _Float16* vrow = Vth + ((size_t)((b * HH + hh) * DD + d)) * NN + rb + wr * 64;
#pragma unroll
            for (int m = 0; m < 4; ++m) {
                f16x4 v4;
#pragma unroll
                for (int r = 0; r < 4; ++r)
                    v4[r] = (_Float16)(accv[m][n][r] + bb);
                *(f16x4*)(vrow + m * 16 + kg * 4) = v4;
            }
        }
    }
}

// ---------------------------------------------------------------------------
// Merged LayerNorm: rows [0, BB*NN) = K (scale 1), rows [BB*NN, +BB*MM) = Q
// (scale 1/sqrt(D)). f16 in -> f16 out. One dispatch for both.
// ---------------------------------------------------------------------------
__global__ __launch_bounds__(256) void ln_rows_f16(
    const _Float16* __restrict__ Klin, const _Float16* __restrict__ Qlin,
    _Float16* __restrict__ Kh, _Float16* __restrict__ Qh,
    const float* __restrict__ gk, const float* __restrict__ bkln,
    const float* __restrict__ gq, const float* __restrict__ bqln)
{
    int row = blockIdx.x;
    const _Float16* y; _Float16* o;
    const float* g; const float* be; float scale;
    if (row < BB * NN) {
        y = Klin + (size_t)row * CC; o = Kh + (size_t)row * CC;
        g = gk; be = bkln; scale = 1.0f;
    } else {
        row -= BB * NN;
        y = Qlin + (size_t)row * CC; o = Qh + (size_t)row * CC;
        g = gq; be = bqln; scale = SCALEF;
    }
    const int tid = threadIdx.x;
    float x0 = (float)y[tid], x1 = (float)y[tid + 256], x2 = (float)y[tid + 512];
    float s = x0 + x1 + x2;
    float q = x0 * x0 + x1 * x1 + x2 * x2;
#pragma unroll
    for (int o2 = 32; o2 >= 1; o2 >>= 1) {
        s += __shfl_xor(s, o2, 64);
        q += __shfl_xor(q, o2, 64);
    }
    __shared__ float sh_s[4], sh_q[4];
    const int w = tid >> 6;
    if ((tid & 63) == 0) { sh_s[w] = s; sh_q[w] = q; }
    __syncthreads();
    s = sh_s[0] + sh_s[1] + sh_s[2] + sh_s[3];
    q = sh_q[0] + sh_q[1] + sh_q[2] + sh_q[3];
    const float mu  = s * (1.f / 768.f);
    const float var = q * (1.f / 768.f) - mu * mu;
    const float inv = rsqrtf(var + LN_EPSF);
    o[tid]       = (_Float16)(((x0 - mu) * inv * g[tid]       + be[tid])       * scale);
    o[tid + 256] = (_Float16)(((x1 - mu) * inv * g[tid + 256] + be[tid + 256]) * scale);
    o[tid + 512] = (_Float16)(((x2 - mu) * inv * g[tid + 512] + be[tid + 512]) * scale);
}

// ---------------------------------------------------------------------------
// Attention stage 1: partial softmax stats per (b,h,32 q-rows, 1024-n slice).
// grid = 1536: mt-major (round-8 known-good config).
// Writes stats[((bh*8+mt)*32 + qrow)*8 + ns*2] = (max, sumexp).
// ---------------------------------------------------------------------------
__global__ __launch_bounds__(256, 4) void attn_stats(
    const _Float16* __restrict__ Qh,   // [B][256][768] LN'd, *SCALE
    const _Float16* __restrict__ Kh,   // [B][4096][768] LN'd
    float* __restrict__ stats)
{
    __shared__ __align__(16) unsigned char smem[37888];
    _Float16* Kl = (_Float16*)smem;                    // [2][128][64] 32KB
    _Float16* Ql = (_Float16*)(smem + 32768);          // [32][64]      4KB
    float (*red)[32][2] = (float(*)[32][2])(smem + 36864);  // 1KB

    const int tid = threadIdx.x;
    const int w = tid >> 6, lane = tid & 63;
    const int l5 = lane >> 5, lm = lane & 31;
    const int bid = blockIdx.x;
    const int mt = bid / 192;
    const int rem = bid % 192;
    const int bh = rem >> 2, ns = rem & 3;
    const int h = bh % HH, b = bh / HH;
    const int qr0 = mt * 32;
    const int nb = ns * 1024;

#define STAGEK(sel, c0)                                                         \
    _Pragma("unroll")                                                           \
    for (int i = 0; i < 4; ++i) {                                               \
        const int L = i * 256 + tid;                                            \
        const int n = L >> 3, pos = L & 7;                                      \
        gldh(Kh + (size_t)(b * NN + (c0) + n) * CC + h * DD + ((pos ^ (n & 7)) << 3), \
             &Kl[(sel) * 8192 + (i * 256 + w * 64) * 8]);                       \
    }

    {   // stage Q tile (32 rows x 64 d), swizzled
        const int n = tid >> 3, pos = tid & 7;
        gldh(Qh + (size_t)(b * MM + qr0 + n) * CC + h * DD + ((pos ^ (n & 7)) << 3),
             &Ql[(w * 64) * 8]);
    }
    STAGEK(0, nb);
    __syncthreads();
    f16x8 qf[4];
#pragma unroll
    for (int ks = 0; ks < 4; ++ks)
        qf[ks] = *(const f16x8*)&Ql[lm * 64 + (((ks * 2 + l5) ^ (lm & 7)) << 3)];

    const int nl = w * 32 + lm;

    float mrun = -1e30f, srun = 0.f;
    int cur = 0;
    for (int c = 0; c < 8; ++c) {
        if (c) __syncthreads();
        if (c + 1 < 8) STAGEK(cur ^ 1, nb + (c + 1) * 128);
        const _Float16* Kb = Kl + cur * 8192;
        f32x16 s;
#pragma unroll
        for (int r = 0; r < 16; ++r) s[r] = 0.f;
        __builtin_amdgcn_s_setprio(1);
#pragma unroll
        for (int ks = 0; ks < 4; ++ks) {
            f16x8 kf = *(const f16x8*)&Kb[nl * 64 + (((ks * 2 + l5) ^ (nl & 7)) << 3)];
            s = __builtin_amdgcn_mfma_f32_32x32x16_f16(kf, qf[ks], s, 0, 0, 0);
        }
        __builtin_amdgcn_s_setprio(0);
        float cmax = s[0];
#pragma unroll
        for (int r = 1; r < 16; ++r) cmax = fmaxf(cmax, s[r]);
        cmax = fmaxf(cmax, __shfl_xor(cmax, 32, 64));
        const float nm = fmaxf(mrun, cmax);
        float cs = 0.f;
#pragma unroll
        for (int r = 0; r < 16; ++r) cs += __expf(s[r] - nm);
        cs += __shfl_xor(cs, 32, 64);
        srun = srun * __expf(mrun - nm) + cs;
        mrun = nm;
        cur ^= 1;
    }
    if (lane < 32) { red[w][lane][0] = mrun; red[w][lane][1] = srun; }
    __syncthreads();
    if (w == 0 && lane < 32) {
        float M = -1e30f;
#pragma unroll
        for (int ww = 0; ww < 4; ++ww) M = fmaxf(M, red[ww][lane][0]);
        float S = 0.f;
#pragma unroll
        for (int ww = 0; ww < 4; ++ww) S += red[ww][lane][1] * __expf(red[ww][lane][0] - M);
        float* sp = stats + ((size_t)((bh * 8 + mt) * 32 + lane)) * 8 + ns * 2;
        sp[0] = M; sp[1] = S;
    }
#undef STAGEK
}

// ---------------------------------------------------------------------------
// Attention stage 2: round-15 structure (full-line NT P store + counted
// vmcnt barrier). Per (b,h,32 q-rows), FULL n range, grid 384.
// ---------------------------------------------------------------------------
__global__ __launch_bounds__(256, 2) void attn_main(
    const _Float16* __restrict__ Qh, const _Float16* __restrict__ Kh,
    const _Float16* __restrict__ Vt,   // [B*H][64][4096]
    const float* __restrict__ stats, const float* __restrict__ qtok,
    float* __restrict__ attn, float* __restrict__ out0)
{
    __shared__ __align__(16) unsigned char smem[77824];
    _Float16* Kl = (_Float16*)smem;                    // [2][128][64] 32KB
    _Float16* Vl = (_Float16*)(smem + 32768);          // [2][64][128] 32KB
    _Float16* Ql = (_Float16*)(smem + 65536);          // [32][64]      4KB
    _Float16* Pl = (_Float16*)(smem + 69632);          // [32][128]     8KB
    float* rbuf = (float*)smem;                        // epilogue 32KB

    const int tid = threadIdx.x;
    const int w = tid >> 6, lane = tid & 63;
    const int l5 = lane >> 5, lm = lane & 31;
    const int bh = blockIdx.x % 48;        // bh-minor: same bh -> same XCD
    const int mt = blockIdx.x / 48;
    const int h = bh % HH, b = bh / HH;
    const int qr0 = mt * 32;

#define STAGEK(sel, c0)                                                         \
    _Pragma("unroll")                                                           \
    for (int i = 0; i < 4; ++i) {                                               \
        const int L = i * 256 + tid;                                            \
        const int n = L >> 3, pos = L & 7;                                      \
        gldh(Kh + (size_t)(b * NN + (c0) + n) * CC + h * DD + ((pos ^ (n & 7)) << 3), \
             &Kl[(sel) * 8192 + (i * 256 + w * 64) * 8]);                       \
    }
#define STAGEV(sel, c0)                                                         \
    _Pragma("unroll")                                                           \
    for (int i = 0; i < 4; ++i) {                                               \
        const int L = i * 256 + tid;                                            \
        const int d = L >> 4, pos = L & 15;                                     \
        const int blk = (pos & 8) | ((pos & 7) ^ (d & 7));                      \
        gldh(Vt + (size_t)(bh * DD + d) * NN + (c0) + blk * 8,                  \
             &Vl[(sel) * 8192 + (i * 256 + w * 64) * 8]);                       \
    }

    // merged global stats for this lane's q-row
    float M, invS;
    {
        const float* sp = stats + ((size_t)((bh * 8 + mt) * 32 + lm)) * 8;
        M = -1e30f;
#pragma unroll
        for (int n2 = 0; n2 < 4; ++n2) M = fmaxf(M, sp[n2 * 2]);
        float S = 0.f;
#pragma unroll
        for (int n2 = 0; n2 < 4; ++n2) S += sp[n2 * 2 + 1] * __expf(sp[n2 * 2] - M);
        invS = 1.f / S;
    }

    {   // stage Q tile
        const int n = tid >> 3, pos = tid & 7;
        gldh(Qh + (size_t)(b * MM + qr0 + n) * CC + h * DD + ((pos ^ (n & 7)) << 3),
             &Ql[(w * 64) * 8]);
    }
    STAGEK(0, 0); STAGEV(0, 0);
    __syncthreads();
    f16x8 qf[4];
#pragma unroll
    for (int ks = 0; ks < 4; ++ks)
        qf[ks] = *(const f16x8*)&Ql[lm * 64 + (((ks * 2 + l5) ^ (lm & 7)) << 3)];

    const int nl = w * 32 + lm;

    f32x16 oacc[2];
#pragma unroll
    for (int dt = 0; dt < 2; ++dt)
#pragma unroll
        for (int r = 0; r < 16; ++r) oacc[dt][r] = 0.f;

    int cur = 0;
    for (int c = 0; c < 32; ++c) {
        if (c) {
            // wait the 8 staging loads (oldest); leave <=4 NT stores in flight
            asm volatile("s_waitcnt vmcnt(4)" ::: "memory");
            __builtin_amdgcn_s_barrier();
            __builtin_amdgcn_sched_barrier(0);
        }
        if (c + 1 < 32) { STAGEK(cur ^ 1, (c + 1) * 128); STAGEV(cur ^ 1, (c + 1) * 128); }
        __builtin_amdgcn_sched_barrier(0);   // pin: loads issue before NT stores
        const _Float16* Kb = Kl + cur * 8192;
        const _Float16* Vb = Vl + cur * 8192;
        f32x16 s;
#pragma unroll
        for (int r = 0; r < 16; ++r) s[r] = 0.f;
        __builtin_amdgcn_s_setprio(1);
#pragma unroll
        for (int ks = 0; ks < 4; ++ks) {
            f16x8 kf = *(const f16x8*)&Kb[nl * 64 + (((ks * 2 + l5) ^ (nl & 7)) << 3)];
            s = __builtin_amdgcn_mfma_f32_32x32x16_f16(kf, qf[ks], s, 0, 0, 0);
        }
        __builtin_amdgcn_s_setprio(0);
        // P -> LDS (f16, swizzled) only; global store happens via readback
#pragma unroll
        for (int q = 0; q < 4; ++q) {
            f16x4 ph;
#pragma unroll
            for (int r = 0; r < 4; ++r)
                ph[r] = (_Float16)(__expf(s[q * 4 + r] - M) * invS);
            const int blk16 = w * 4 + q;
            const int pos = (blk16 & 8) | ((blk16 & 7) ^ (lm & 7));
            *(f16x4*)&Pl[lm * 128 + pos * 8 + l5 * 4] = ph;
        }
        __builtin_amdgcn_s_setprio(1);
#pragma unroll
        for (int ks = 0; ks < 2; ++ks) {
            const int blk16 = w * 4 + ks * 2 + l5;
            const int posP = (blk16 & 8) | ((blk16 & 7) ^ (lm & 7));
            f16x8 pf = *(const f16x8*)&Pl[lm * 128 + posP * 8];
#pragma unroll
            for (int dt = 0; dt < 2; ++dt) {
                const int d = dt * 32 + lm;
                const int posV = (blk16 & 8) | ((blk16 & 7) ^ (d & 7));
                f16x8 vf = *(const f16x8*)&Vb[d * 128 + posV * 8];
                oacc[dt] = __builtin_amdgcn_mfma_f32_32x32x16_f16(pf, vf, oacc[dt], 0, 0, 0);
            }
        }
        __builtin_amdgcn_s_setprio(0);
        // Full-line NT writeback of this wave's own n-window (all 32 rows):
        // 4 lanes x 16B cover each 64B line within one instruction.
#pragma unroll
        for (int p = 0; p < 4; ++p) {
            const int pr = p >> 1, nh = p & 1;
            const int row = pr * 16 + (lane >> 2);       // 0..31
            const int k = lane & 3;
            const int nn = nh * 16 + k * 4;              // within wave's 32-n
            const int j = w * 4 + (nn >> 3);
            const int swz = (j & 8) | ((j & 7) ^ (row & 7));
            f16x4 pv4 = *(const f16x4*)&Pl[row * 128 + swz * 8 + (nn & 7)];
            f32x4 o4;
            o4[0] = (float)pv4[0]; o4[1] = (float)pv4[1];
            o4[2] = (float)pv4[2]; o4[3] = (float)pv4[3];
            __builtin_nontemporal_store(o4,
                (f32x4*)(attn + ((size_t)(bh * MM + qr0 + row)) * NN
                         + c * 128 + w * 32 + nn));
        }
        cur ^= 1;
    }

    // epilogue: cross-wave reduce + residual
    __syncthreads();
#pragma unroll
    for (int dt = 0; dt < 2; ++dt)
#pragma unroll
        for (int r = 0; r < 16; ++r) {
            const int mrow = (r & 3) + 8 * (r >> 2) + 4 * l5;
            rbuf[w * 2048 + mrow * 64 + dt * 32 + lm] = oacc[dt][r];
        }
    __syncthreads();
    {
        const int m = tid >> 3, d0 = (tid & 7) * 8;
        const size_t obase = (size_t)(b * MM + qr0 + m) * CC + h * DD + d0;
        f32x4 v0, v1;
#pragma unroll
        for (int j = 0; j < 4; ++j) {
            const int idx = m * 64 + d0 + j;
            v0[j] = rbuf[idx] + rbuf[2048 + idx] + rbuf[4096 + idx] + rbuf[6144 + idx];
        }
#pragma unroll
        for (int j = 0; j < 4; ++j) {
            const int idx = m * 64 + d0 + 4 + j;
            v1[j] = rbuf[idx] + rbuf[2048 + idx] + rbuf[4096 + idx] + rbuf[6144 + idx];
        }
        float4 q0 = *(const float4*)(qtok + obase);
        float4 q1 = *(const float4*)(qtok + obase + 4);
        v0[0] += q0.x; v0[1] += q0.y; v0[2] += q0.z; v0[3] += q0.w;
        v1[0] += q1.x; v1[1] += q1.y; v1[2] += q1.z; v1[3] += q1.w;
        *(f32x4*)(out0 + obase) = v0;
        *(f32x4*)(out0 + obase + 4) = v1;
    }
#undef STAGEK
#undef STAGEV
}

extern "C" void kernel_launch(void* const* d_in, const int* in_sizes, int n_in,
                              void* d_out, int out_size, void* d_ws, size_t ws_size,
                              hipStream_t stream) {
    (void)in_sizes; (void)n_in; (void)out_size; (void)ws_size;
    const float* input_tokens = (const float*)d_in[0];
    const float* query_tokens = (const float*)d_in[1];
    const float* Wq   = (const float*)d_in[2];
    const float* bq   = (const float*)d_in[3];
    const float* Wk   = (const float*)d_in[4];
    const float* bk   = (const float*)d_in[5];
    const float* Wv   = (const float*)d_in[6];
    const float* bv   = (const float*)d_in[7];
    const float* gq   = (const float*)d_in[8];
    const float* bqln = (const float*)d_in[9];
    const float* gk   = (const float*)d_in[10];
    const float* bkln = (const float*)d_in[11];

    float* out0 = (float*)d_out;
    float* attn = out0 + (size_t)BB * MM * CC;

    _Float16* hptr = (_Float16*)d_ws;
    _Float16* Klin = hptr;                              // [B*N][C]
    _Float16* Qlin = Klin + (size_t)BB * NN * CC;       // [B*M][C]
    _Float16* Wkh  = Qlin + (size_t)BB * MM * CC;       // [C][C]
    _Float16* Wqh  = Wkh  + (size_t)CC * CC;
    _Float16* Wvh  = Wqh  + (size_t)CC * CC;
    _Float16* Kh   = Wvh  + (size_t)CC * CC;            // post-LN K
    _Float16* Qh   = Kh   + (size_t)BB * NN * CC;       // post-LN Q
    _Float16* Vt   = Qh   + (size_t)BB * MM * CC;       // [48][64][4096]
    float* stats   = (float*)(Vt + (size_t)BB * HH * DD * NN);  // [12288][4][2]

    // --- weight f32->f16 conversions only (X converts inside proj) ---
    conv_w<<<512, 256, 0, stream>>>(Wk, Wkh, Wq, Wqh, Wv, Wvh);

    // --- K+V fused projection (+Q blocks); A reg-staged from f32 inputs ---
    proj_kv_f16<<<816, 256, 0, stream>>>(input_tokens, query_tokens,
                                         Wkh, Wqh, Wvh,
                                         bk, bq, bv, Klin, Qlin, Vt);

    // --- merged LayerNorm (K rows then Q rows) -> f16 ---
    ln_rows_f16<<<BB * NN + BB * MM, 256, 0, stream>>>(Klin, Qlin, Kh, Qh,
                                                       gk, bkln, gq, bqln);

    // --- attention: high-occupancy stats sweep, then full-range main ---
    attn_stats<<<1536, 256, 0, stream>>>(Qh, Kh, stats);
    attn_main<<<384, 256, 0, stream>>>(Qh, Kh, Vt, stats, query_tokens, attn, out0);
}